// Round 18
// baseline (821.880 us; speedup 1.0000x reference)
//
#include <hip/hip_runtime.h>
#include <hip/hip_bf16.h>

#define BB 64
#define TT 12
#define NN 207
#define DD 128
#define HH 8
#define DH 16
#define MROWS (BB*TT*NN)   // 158976 = 621*256 = 2484*64
#define KPAD 224
#define AW 768             // abuf width: [x | xs1 | s0 | t0 | s1 | t1] each 128
#define CHB 32
#define CROWS (CHB*TT*NN)  // 79488 = 4968*16

typedef __bf16 bf16x8 __attribute__((ext_vector_type(8)));
typedef __bf16 bf16x4 __attribute__((ext_vector_type(4)));
typedef float  f32x4  __attribute__((ext_vector_type(4)));

__device__ inline float  b2f(__bf16 v){ return (float)v; }
__device__ inline __bf16 f2b(float v){ return (__bf16)v; }
__device__ inline bf16x8 ldfrag(const __bf16* p){ return *reinterpret_cast<const bf16x8*>(p); }

__device__ inline void gload_lds16(const __bf16* g, __bf16* l){
    __builtin_amdgcn_global_load_lds(
        (const __attribute__((address_space(1))) void*)(g),
        (__attribute__((address_space(3))) void*)(l), 16, 0, 0);
}
__device__ inline int swz(int r){ return (r ^ (r>>2)) & 3; }
__device__ inline int pkey(int c){ return (c + (c>>2)) & 3; }

// ---------------- x (f32) -> abuf[:,0:128] bf16 ----------------
__global__ __launch_bounds__(256) void xcopy_kernel(const float* __restrict__ x, __bf16* __restrict__ abuf)
{
    int nt = gridDim.x*256;
    for (int gIdx = blockIdx.x*256 + threadIdx.x; gIdx < MROWS*16; gIdx += nt) {
        int row = gIdx >> 4, c8 = (gIdx & 15)*8;
        const float* s = x + (size_t)row*DD + c8;
        f32x4 a = *reinterpret_cast<const f32x4*>(s);
        f32x4 b = *reinterpret_cast<const f32x4*>(s+4);
        bf16x8 r;
        #pragma unroll
        for (int i=0;i<4;i++){ r[i] = f2b(a[i]); r[i+4] = f2b(b[i]); }
        *reinterpret_cast<bf16x8*>(abuf + (size_t)row*AW + c8) = r;
    }
}

// ---------------- misc prep ----------------
__global__ __launch_bounds__(256) void prep_misc_kernel(
    const float* __restrict__ graph, const float* __restrict__ qkv_w,
    const float* __restrict__ out_w, const float* __restrict__ out_b,
    const float* __restrict__ pw_w,  const float* __restrict__ pw_b,
    const float* __restrict__ fc1_w, const float* __restrict__ fc2_w,
    __bf16* __restrict__ gpad, __bf16* __restrict__ qkv_wb, __bf16* __restrict__ wcomb,
    __bf16* __restrict__ fc1_wb, __bf16* __restrict__ fc2_wb, float* __restrict__ bias_comb)
{
    int nt = gridDim.x*256;
    int tid = blockIdx.x*256 + threadIdx.x;
    for (int i = tid; i < TT*NN*KPAD; i += nt) {
        int k = i % KPAD, r = i / KPAD;
        gpad[i] = (k < NN) ? f2b(graph[(size_t)r*NN + k]) : f2b(0.f);
    }
    for (int i = tid; i < 2*3*DD*DD; i += nt) qkv_wb[i] = f2b(qkv_w[i]);
    for (int i = tid; i < DD*AW; i += nt) {
        int c = i / AW, j = i % AW;
        float v;
        if      (j < 128) v = pw_w[c*128 + j];
        else if (j < 256) v = pw_w[128*128 + c*128 + (j-128)];
        else if (j < 512) v = out_w[c*256 + (j-256)];
        else              v = out_w[128*256 + c*256 + (j-512)];
        wcomb[i] = f2b(v);
    }
    for (int i = tid; i < 2*DD*DD; i += nt) fc1_wb[i] = f2b(fc1_w[i]);
    for (int i = tid; i < 2*DD*DD; i += nt) fc2_wb[i] = f2b(fc2_w[i]);
    for (int i = tid; i < DD; i += nt)
        bias_comb[i] = pw_b[i] + pw_b[128+i] + out_b[i] + out_b[128+i];
}

// ---------------- propagate: abuf[:,128:256] = graph[t] @ abuf[:,0:128]  per (b,t) ----------------
__global__ __launch_bounds__(256) void propagate_kernel(const __bf16* __restrict__ gp,
    __bf16* __restrict__ abuf)
{
    int bt   = blockIdx.x;
    int t    = bt % TT;
    int tile = blockIdx.y;
    int lane = threadIdx.x & 63, w = threadIdx.x >> 6;
    int lhi = lane >> 4, llo = lane & 15;
    __shared__ __attribute__((aligned(16))) __bf16 XT[DD][40];
    const __bf16* xbt  = abuf + (size_t)bt*NN*AW;
    const __bf16* grow = gp + (size_t)t*NN*KPAD;
    int rowbase = tile*64 + w*16;
    f32x4 acc[8];
    #pragma unroll
    for (int i=0;i<8;i++) acc[i] = (f32x4){0.f,0.f,0.f,0.f};
    int arow = rowbase + llo; if (arow > NN-1) arow = NN-1;
    for (int k0=0; k0<KPAD; k0+=32) {
        __syncthreads();
        for (int kl = (threadIdx.x>>7); kl < 32; kl += 2) {
            int kk = k0 + kl, c = threadIdx.x & 127;
            __bf16 xb = (kk < NN) ? xbt[(size_t)kk*AW + c] : f2b(0.f);
            XT[c][(((kl>>3) ^ pkey(c))<<3) | (kl&7)] = xb;
        }
        __syncthreads();
        bf16x8 a = ldfrag(grow + (size_t)arow*KPAD + k0 + lhi*8);
        #pragma unroll
        for (int cf=0;cf<8;cf++){
            int row = cf*16+llo;
            bf16x8 b = *reinterpret_cast<const bf16x8*>(&XT[row][(lhi ^ pkey(row))<<3]);
            acc[cf] = __builtin_amdgcn_mfma_f32_16x16x32_bf16(a, b, acc[cf], 0,0,0);
        }
    }
    #pragma unroll
    for (int e=0;e<4;e++){
        int row = rowbase + lhi*4 + e;
        if (row < NN) {
            #pragma unroll
            for (int cf=0;cf<8;cf++)
                abuf[((size_t)bt*NN + row)*AW + DD + cf*16 + llo] = f2b(acc[cf][e]);
        }
    }
}

// ---------------- R7 LDS-staged GEMM (512 thr, 256x128, ring-3, counted vmcnt) ----------------
// MODE 3: out_bf16 = LN(resid + acc + bias)
template<int MODE, bool RELU>
__global__ __launch_bounds__(512) void gemm_kernel(const __bf16* __restrict__ A, size_t lda,
    const __bf16* __restrict__ W, const float* __restrict__ bias,
    void* out, size_t ldc, int K, int mend,
    const __bf16* __restrict__ resid, size_t ldr,
    const float* __restrict__ lng, const float* __restrict__ lnb)
{
    __shared__ __attribute__((aligned(16))) __bf16 lds[3][12288];
    int w = threadIdx.x >> 6, lane = threadIdx.x & 63;
    int lhi = lane >> 4, llo = lane & 15;
    size_t row0 = (size_t)blockIdx.x*256;
    int col0 = blockIdx.y*128;
    int nt = K >> 5;

    int sA0 = (w*2+0)*64 + lane, sA1 = (w*2+1)*64 + lane, sW = w*64 + lane;
    int rA0 = sA0>>2, uA0 = sA0&3, rA1 = sA1>>2, uA1 = sA1&3, rW = sW>>2, uW = sW&3;
    long gr0 = (long)row0 + rA0; if (gr0 >= mend) gr0 = mend-1;
    long gr1 = (long)row0 + rA1; if (gr1 >= mend) gr1 = mend-1;
    const __bf16* gA0 = A + (size_t)gr0*lda + ((uA0 ^ swz(rA0))<<3);
    const __bf16* gA1 = A + (size_t)gr1*lda + ((uA1 ^ swz(rA1))<<3);
    const __bf16* gW  = W + (size_t)(col0 + rW)*K + ((uW ^ swz(rW))<<3);
    __bf16* base0 = &lds[0][0];

    int aoff[2], woff[8];
    #pragma unroll
    for (int rt=0;rt<2;rt++){
        int rl = w*32 + rt*16 + llo;
        aoff[rt] = rl*32 + ((lhi ^ swz(rl))<<3);
    }
    #pragma unroll
    for (int cf=0;cf<8;cf++){
        int wr = cf*16 + llo;
        woff[cf] = 8192 + wr*32 + ((lhi ^ swz(wr))<<3);
    }

    f32x4 acc[2][8];
    #pragma unroll
    for (int i=0;i<2;i++)
        #pragma unroll
        for (int j=0;j<8;j++) acc[i][j] = (f32x4){0.f,0.f,0.f,0.f};

    #define STAGE(buf, tt) { int k0 = (tt)<<5; __bf16* Lw = base0 + (buf)*12288;           \
        gload_lds16(gA0 + k0, Lw + (w*2+0)*512);                                           \
        gload_lds16(gA1 + k0, Lw + (w*2+1)*512);                                           \
        gload_lds16(gW  + k0, Lw + 8192 + w*512); }

    STAGE(0,0); STAGE(1,1); STAGE(2,2);

    int cur = 0;
    for (int t = 0; t < nt; ++t) {
        if (t <= nt-3)      asm volatile("s_waitcnt vmcnt(6)" ::: "memory");
        else if (t == nt-2) asm volatile("s_waitcnt vmcnt(3)" ::: "memory");
        else                asm volatile("s_waitcnt vmcnt(0)" ::: "memory");
        __builtin_amdgcn_s_barrier();
        __builtin_amdgcn_sched_barrier(0);
        const __bf16* Lb = base0 + cur*12288;
        bf16x8 a[2], b[8];
        #pragma unroll
        for (int rt=0;rt<2;rt++) a[rt] = *reinterpret_cast<const bf16x8*>(&Lb[aoff[rt]]);
        #pragma unroll
        for (int cf=0;cf<8;cf++)  b[cf] = *reinterpret_cast<const bf16x8*>(&Lb[woff[cf]]);
        asm volatile("s_waitcnt lgkmcnt(0)" ::: "memory");
        __builtin_amdgcn_sched_barrier(0);
        __builtin_amdgcn_s_barrier();
        if (t+3 < nt) STAGE(cur, t+3);
        #pragma unroll
        for (int rt=0;rt<2;rt++)
            #pragma unroll
            for (int cf=0;cf<8;cf++)
                acc[rt][cf] = __builtin_amdgcn_mfma_f32_16x16x32_bf16(a[rt], b[cf], acc[rt][cf], 0,0,0);
        cur = (cur == 2) ? 0 : cur + 1;
    }
    #undef STAGE

    float bv[8];
    #pragma unroll
    for (int cf=0;cf<8;cf++) bv[cf] = bias ? bias[col0 + cf*16 + llo] : 0.f;

    if (MODE == 0) {
        #pragma unroll
        for (int rt=0;rt<2;rt++) {
            #pragma unroll
            for (int e=0;e<4;e++) {
                size_t row = row0 + (size_t)w*32 + rt*16 + lhi*4 + e;
                if ((long)row >= mend) continue;
                #pragma unroll
                for (int cf=0;cf<8;cf++) {
                    float v = acc[rt][cf][e] + bv[cf];
                    if (RELU) v = fmaxf(v, 0.f);
                    ((__bf16*)out)[row*ldc + col0 + cf*16 + llo] = f2b(v);
                }
            }
        }
    } else {
        float g8[8], b8[8];
        #pragma unroll
        for (int cf=0;cf<8;cf++){ int c = cf*16 + llo; g8[cf] = lng[c]; b8[cf] = lnb[c]; }
        #pragma unroll
        for (int rt=0;rt<2;rt++) {
            #pragma unroll
            for (int e=0;e<4;e++) {
                size_t row = row0 + (size_t)w*32 + rt*16 + lhi*4 + e;
                if ((long)row >= mend) continue;
                float vals[8], s = 0.f, ss = 0.f;
                #pragma unroll
                for (int cf=0;cf<8;cf++) {
                    int c = cf*16 + llo;
                    float r = b2f(resid[row*ldr + c]);
                    float v = acc[rt][cf][e] + bv[cf] + r;
                    vals[cf] = v; s += v; ss += v*v;
                }
                #pragma unroll
                for (int o=1;o<16;o<<=1){ s += __shfl_xor(s,o,64); ss += __shfl_xor(ss,o,64); }
                float mean = s * (1.f/DD);
                float var  = ss * (1.f/DD) - mean*mean;
                float rs   = rsqrtf(var + 1e-5f);
                #pragma unroll
                for (int cf=0;cf<8;cf++) {
                    float v = (vals[cf]-mean)*rs*g8[cf] + b8[cf];
                    ((__bf16*)out)[row*ldc + cf*16 + llo] = f2b(v);
                }
            }
        }
    }
}

// ---------------- streaming K=128 GEMM: W in VGPRs, wave-private LDS ring-3, no barriers ----
template<bool RELU>
__global__ __launch_bounds__(256) void sgemm_k128(const __bf16* __restrict__ A, size_t lda,
    const __bf16* __restrict__ W, const float* __restrict__ bias,
    __bf16* __restrict__ out, size_t ldc, int ngroups)
{
    __shared__ __attribute__((aligned(16))) __bf16 lds[12][2048];
    int w = threadIdx.x >> 6, lane = threadIdx.x & 63;
    int lhi = lane >> 4, llo = lane & 15;
    int col0 = blockIdx.y*128;

    bf16x8 wf[4][8];
    #pragma unroll
    for (int ks=0;ks<4;ks++)
        #pragma unroll
        for (int cf=0;cf<8;cf++)
            wf[ks][cf] = ldfrag(W + (size_t)(col0 + cf*16 + llo)*128 + ks*32 + lhi*8);

    f32x4 bvv[8];
    #pragma unroll
    for (int cf=0;cf<8;cf++){
        if (bias) bvv[cf] = *reinterpret_cast<const f32x4*>(bias + col0 + cf*16 + lhi*4);
        else      bvv[cf] = (f32x4){0.f,0.f,0.f,0.f};
    }

    size_t gsrc[4];
    #pragma unroll
    for (int j=0;j<4;j++){
        int r = j*4 + lhi;
        int u = llo ^ r;
        gsrc[j] = (size_t)r*lda + (size_t)u*8;
    }
    int aoff[4];
    #pragma unroll
    for (int ks=0;ks<4;ks++) aoff[ks] = llo*128 + (((ks<<2)|lhi) ^ llo)*8;

    int gw = blockIdx.x*4 + w, stride = gridDim.x*4;
    int n = (gw < ngroups) ? ((ngroups-1-gw)/stride + 1) : 0;
    __bf16* slab0 = &lds[w*3][0];

    #define SSTAGE(i) { size_t rbase = (size_t)(gw + (size_t)(i)*stride)*16*lda;           \
        __bf16* L = slab0 + ((i)%3)*2048;                                                  \
        gload_lds16(A + rbase + gsrc[0], L);                                               \
        gload_lds16(A + rbase + gsrc[1], L + 512);                                         \
        gload_lds16(A + rbase + gsrc[2], L + 1024);                                        \
        gload_lds16(A + rbase + gsrc[3], L + 1536); }

    if (n > 0) SSTAGE(0);
    if (n > 1) SSTAGE(1);

    for (int i = 0; i < n; ++i) {
        int kept = ((i+1 < n) ? 4 : 0) + ((i >= 2) ? 16 : i*8);
        if      (kept >= 20) asm volatile("s_waitcnt vmcnt(20)" ::: "memory");
        else if (kept == 16) asm volatile("s_waitcnt vmcnt(16)" ::: "memory");
        else if (kept == 12) asm volatile("s_waitcnt vmcnt(12)" ::: "memory");
        else if (kept == 8)  asm volatile("s_waitcnt vmcnt(8)"  ::: "memory");
        else if (kept == 4)  asm volatile("s_waitcnt vmcnt(4)"  ::: "memory");
        else                 asm volatile("s_waitcnt vmcnt(0)"  ::: "memory");

        const __bf16* Ls = slab0 + (i%3)*2048;
        bf16x8 a[4];
        #pragma unroll
        for (int ks=0;ks<4;ks++) a[ks] = *reinterpret_cast<const bf16x8*>(&Ls[aoff[ks]]);

        if (i+2 < n) SSTAGE(i+2);

        f32x4 acc[8];
        #pragma unroll
        for (int cf=0;cf<8;cf++) acc[cf] = (f32x4){0.f,0.f,0.f,0.f};
        #pragma unroll
        for (int ks=0;ks<4;ks++)
            #pragma unroll
            for (int cf=0;cf<8;cf++)
                acc[cf] = __builtin_amdgcn_mfma_f32_16x16x32_bf16(wf[ks][cf], a[ks], acc[cf], 0,0,0);

        size_t grow = (size_t)(gw + (size_t)i*stride)*16 + llo;
        #pragma unroll
        for (int cf=0;cf<8;cf++){
            bf16x4 o;
            #pragma unroll
            for (int e=0;e<4;e++){
                float v = acc[cf][e] + bvv[cf][e];
                if (RELU) v = fmaxf(v, 0.f);
                o[e] = f2b(v);
            }
            *reinterpret_cast<bf16x4*>(out + grow*ldc + col0 + cf*16 + lhi*4) = o;
        }
    }
    #undef SSTAGE
}

// ---------------- fused FFN (64-row blocks, ring-2 prologue-staged) ----------
__global__ __launch_bounds__(256) void ffn_kernel(const __bf16* __restrict__ h,
    const __bf16* __restrict__ w1, const float* __restrict__ b1,
    const __bf16* __restrict__ w2, const float* __restrict__ b2,
    const float* __restrict__ lng, const float* __restrict__ lnb,
    float* __restrict__ dout)
{
    __shared__ __attribute__((aligned(16))) __bf16 hring[2][4096];
    __shared__ __attribute__((aligned(16))) __bf16 f1b[8192];
    __shared__ float fl2[2][32][4][2];
    int w = threadIdx.x >> 6, lane = threadIdx.x & 63;
    int lhi = lane >> 4, llo = lane & 15;
    size_t row0 = (size_t)blockIdx.x * 64;

    size_t gsrc[2]; int ldst[2];
    #pragma unroll
    for (int j=0;j<2;j++){
        int i = w*64 + lane + 256*j;
        int r = i >> 4, u = i & 15;
        gsrc[j] = (size_t)r*AW + ((u ^ (r & 15)) << 3);
        ldst[j] = (w*64 + 256*j) * 8;
    }
    #define FSTAGE(slot, g) { const __bf16* src = h + (row0 + (size_t)(g)*32)*AW;          \
        gload_lds16(src + gsrc[0], &hring[slot][0] + ldst[0]);                             \
        gload_lds16(src + gsrc[1], &hring[slot][0] + ldst[1]); }

    f32x4 b1v[4], b2v[2], gv[2], bt2[2];
    #pragma unroll
    for (int c4=0;c4<4;c4++) b1v[c4] = *reinterpret_cast<const f32x4*>(b1 + w*64 + c4*16 + lhi*4);
    #pragma unroll
    for (int c2=0;c2<2;c2++){
        b2v[c2] = *reinterpret_cast<const f32x4*>(b2  + w*32 + c2*16 + lhi*4);
        gv[c2]  = *reinterpret_cast<const f32x4*>(lng + w*32 + c2*16 + lhi*4);
        bt2[c2] = *reinterpret_cast<const f32x4*>(lnb + w*32 + c2*16 + lhi*4);
    }

    FSTAGE(0,0); FSTAGE(1,1);

    for (int g = 0; g < 2; ++g) {
        if (g == 0) asm volatile("s_waitcnt vmcnt(2)" ::: "memory");
        else        asm volatile("s_waitcnt vmcnt(0)" ::: "memory");
        __builtin_amdgcn_s_barrier();
        __builtin_amdgcn_sched_barrier(0);
        const __bf16* Hs = &hring[g][0];

        bf16x8 hb[2][4];
        bf16x4 hres[2][2];
        #pragma unroll
        for (int rf=0;rf<2;rf++){
            int r = rf*16 + llo;
            #pragma unroll
            for (int ks=0;ks<4;ks++)
                hb[rf][ks] = *reinterpret_cast<const bf16x8*>(Hs + r*128 + (((ks*4+lhi) ^ llo) << 3));
            #pragma unroll
            for (int cf=0;cf<2;cf++){
                int unit = w*4 + cf*2 + (lhi>>1);
                hres[cf][rf] = *reinterpret_cast<const bf16x4*>(Hs + r*128 + ((unit ^ llo) << 3) + (lhi & 1)*4);
            }
        }
        asm volatile("s_waitcnt lgkmcnt(0)" ::: "memory");
        __builtin_amdgcn_sched_barrier(0);

        f32x4 acc1[4][2];
        #pragma unroll
        for (int i=0;i<4;i++){ acc1[i][0] = (f32x4){0,0,0,0}; acc1[i][1] = (f32x4){0,0,0,0}; }
        #pragma unroll
        for (int ks=0;ks<4;ks++){
            #pragma unroll
            for (int cf2=0;cf2<4;cf2++){
                bf16x8 wfr = ldfrag(w1 + (size_t)(w*64 + cf2*16 + llo)*128 + ks*32 + lhi*8);
                #pragma unroll
                for (int rf=0;rf<2;rf++)
                    acc1[cf2][rf] = __builtin_amdgcn_mfma_f32_16x16x32_bf16(wfr, hb[rf][ks], acc1[cf2][rf], 0,0,0);
            }
        }
        #pragma unroll
        for (int rf=0;rf<2;rf++){
            int r = rf*16 + llo;
            #pragma unroll
            for (int cf2=0;cf2<4;cf2++){
                bf16x4 o;
                #pragma unroll
                for (int e=0;e<4;e++) o[e] = f2b(fmaxf(acc1[cf2][rf][e] + b1v[cf2][e], 0.f));
                int unit = w*8 + cf2*2 + (lhi>>1);
                *reinterpret_cast<bf16x4*>(&f1b[r*256 + ((unit ^ r) << 3) + (lhi&1)*4]) = o;
            }
        }
        asm volatile("s_waitcnt lgkmcnt(0)" ::: "memory");
        __builtin_amdgcn_sched_barrier(0);
        __builtin_amdgcn_s_barrier();

        f32x4 acc2[2][2];
        acc2[0][0]=(f32x4){0,0,0,0}; acc2[0][1]=(f32x4){0,0,0,0};
        acc2[1][0]=(f32x4){0,0,0,0}; acc2[1][1]=(f32x4){0,0,0,0};
        #pragma unroll
        for (int ks2=0;ks2<8;ks2++){
            bf16x8 fb[2];
            #pragma unroll
            for (int rf=0;rf<2;rf++){
                int r = rf*16 + llo;
                fb[rf] = *reinterpret_cast<const bf16x8*>(&f1b[r*256 + (((ks2*4+lhi) ^ r) << 3)]);
            }
            #pragma unroll
            for (int cf=0;cf<2;cf++){
                bf16x8 wfr = ldfrag(w2 + (size_t)(w*32 + cf*16 + llo)*256 + ks2*32 + lhi*8);
                #pragma unroll
                for (int rf=0;rf<2;rf++)
                    acc2[cf][rf] = __builtin_amdgcn_mfma_f32_16x16x32_bf16(wfr, fb[rf], acc2[cf][rf], 0,0,0);
            }
        }

        float vals[2][2][4]; float s[2] = {0.f,0.f}, ss[2] = {0.f,0.f};
        #pragma unroll
        for (int rf=0;rf<2;rf++)
            #pragma unroll
            for (int cf=0;cf<2;cf++)
                #pragma unroll
                for (int e=0;e<4;e++){
                    float v = acc2[cf][rf][e] + b2v[cf][e] + b2f(hres[cf][rf][e]);
                    vals[rf][cf][e] = v; s[rf] += v; ss[rf] += v*v;
                }
        #pragma unroll
        for (int rf=0;rf<2;rf++){
            s[rf]  += __shfl_xor(s[rf],16,64);  s[rf]  += __shfl_xor(s[rf],32,64);
            ss[rf] += __shfl_xor(ss[rf],16,64); ss[rf] += __shfl_xor(ss[rf],32,64);
            if (lhi == 0){ fl2[g][rf*16+llo][w][0] = s[rf]; fl2[g][rf*16+llo][w][1] = ss[rf]; }
        }
        asm volatile("s_waitcnt lgkmcnt(0)" ::: "memory");
        __builtin_amdgcn_s_barrier();
        #pragma unroll
        for (int rf=0;rf<2;rf++){
            int r = rf*16 + llo;
            float S  = fl2[g][r][0][0]+fl2[g][r][1][0]+fl2[g][r][2][0]+fl2[g][r][3][0];
            float SS = fl2[g][r][0][1]+fl2[g][r][1][1]+fl2[g][r][2][1]+fl2[g][r][3][1];
            float mean = S*(1.f/DD), var = SS*(1.f/DD)-mean*mean, rs = rsqrtf(var+1e-5f);
            size_t grow = row0 + (size_t)g*32 + r;
            #pragma unroll
            for (int cf=0;cf<2;cf++){
                f32x4 o;
                #pragma unroll
                for (int e=0;e<4;e++) o[e] = (vals[rf][cf][e]-mean)*rs*gv[cf][e] + bt2[cf][e];
                *reinterpret_cast<f32x4*>(dout + grow*DD + w*32 + cf*16 + lhi*4) = o;
            }
        }
        if (g == 0) __builtin_amdgcn_s_barrier();
    }
    #undef FSTAGE
}

// ---------------- merged spatial+temporal linear attention ----------------
#define ACH 32
#define SBLKS (CHB*TT*4)
__global__ __launch_bounds__(256) void attn_st_kernel(const __bf16* __restrict__ qkv,
    __bf16* __restrict__ outs, __bf16* __restrict__ outt)
{
    __shared__ __attribute__((aligned(16))) char smem[44032];
    int tid = threadIdx.x;
    int bx = blockIdx.x;

    if (bx < SBLKS) {
        int bt = bx >> 2, g = bx & 3;
        const __bf16* base = qkv + (size_t)bt*NN*384 + g*32;
        __bf16 (*qbuf)[40] = (__bf16(*)[40])(smem);
        __bf16 (*vbuf)[40] = (__bf16(*)[40])(smem + 17920);
        __bf16 (*kbuf)[40] = (__bf16(*)[40])(smem + 35840);
        float (*flk)[16][17] = (float(*)[16][17])(smem + 38400);
        float (*fls)[16]     = (float(*)[16])(smem + 42752);
        int wave = tid >> 6, lane = tid & 63;
        int h2 = tid >> 7;
        int dd = tid & 15;
        int oct = ((tid >> 4) & 3) | ((wave & 1) << 2);
        float kvs_col[16]; float ks = 0.f;
        #pragma unroll
        for (int m=0;m<16;m++) kvs_col[m] = 0.f;

        for (int c0 = 0; c0 < NN; c0 += ACH) {
            __syncthreads();
            for (int i = tid; i < ACH*12; i += 256) {
                int r = i/12, u = i%12, seg = u>>2, uu = u&3;
                int nn = c0 + r;
                bf16x8 v8 = (bf16x8){};
                if (nn < NN) v8 = *reinterpret_cast<const bf16x8*>(base + (size_t)nn*384 + seg*128 + uu*8);
                if      (seg == 0) *reinterpret_cast<bf16x8*>(&qbuf[nn][uu*8]) = v8;
                else if (seg == 1) *reinterpret_cast<bf16x8*>(&kbuf[r][uu*8])  = v8;
                else               *reinterpret_cast<bf16x8*>(&vbuf[nn][uu*8]) = v8;
            }
            __syncthreads();
            #pragma unroll
            for (int j=0;j<4;j++){
                int r = oct + 8*j; int nn = c0 + r;
                if (nn >= NN) continue;   // uniform across the 16-lane dd group
                // cooperative k-norm across dd group (each lane squares 1 element)
                float kdd = b2f(kbuf[r][h2*16+dd]);
                float sk = kdd*kdd;
                sk += __shfl_xor(sk,1,64); sk += __shfl_xor(sk,2,64);
                sk += __shfl_xor(sk,4,64); sk += __shfl_xor(sk,8,64);
                float iv = 1.f/fmaxf(sqrtf(sk), 1e-12f);
                bf16x8 k0 = *reinterpret_cast<const bf16x8*>(&kbuf[r][h2*16]);
                bf16x8 k1 = *reinterpret_cast<const bf16x8*>(&kbuf[r][h2*16+8]);
                float vv  = b2f(vbuf[nn][h2*16+dd]);
                float t2 = iv*vv;
                #pragma unroll
                for (int m=0;m<8;m++){
                    kvs_col[m]   += b2f(k0[m])*t2;
                    kvs_col[m+8] += b2f(k1[m])*t2;
                }
                ks += kdd*iv;
            }
        }
        #pragma unroll
        for (int m=0;m<16;m++){
            kvs_col[m] += __shfl_xor(kvs_col[m], 16, 64);
            kvs_col[m] += __shfl_xor(kvs_col[m], 32, 64);
        }
        ks += __shfl_xor(ks, 16, 64);
        ks += __shfl_xor(ks, 32, 64);
        if (lane < 16){
            #pragma unroll
            for (int m=0;m<16;m++) flk[wave][m][lane] = kvs_col[m];
            fls[wave][lane] = ks;
        }
        __syncthreads();
        float ksr[16];
        #pragma unroll
        for (int m=0;m<16;m++){
            kvs_col[m] += flk[wave^1][m][dd];
            ksr[m] = fls[h2*2][m] + fls[h2*2+1][m];
        }
        for (int nn = oct; nn < NN; nn += 8) {
            // cooperative q-norm across dd group
            float qdd = b2f(qbuf[nn][h2*16+dd]);
            float sq = qdd*qdd;
            sq += __shfl_xor(sq,1,64); sq += __shfl_xor(sq,2,64);
            sq += __shfl_xor(sq,4,64); sq += __shfl_xor(sq,8,64);
            float iq = 1.f/fmaxf(sqrtf(sq), 1e-12f);
            bf16x8 q0 = *reinterpret_cast<const bf16x8*>(&qbuf[nn][h2*16]);
            bf16x8 q1 = *reinterpret_cast<const bf16x8*>(&qbuf[nn][h2*16+8]);
            float num = 0.f, den = 0.f;
            #pragma unroll
            for (int m=0;m<8;m++){
                float qm0 = b2f(q0[m]), qm1 = b2f(q1[m]);
                num += qm0*kvs_col[m] + qm1*kvs_col[m+8];
                den += qm0*ksr[m]     + qm1*ksr[m+8];
            }
            float vv = b2f(vbuf[nn][h2*16+dd]);
            float o = (num*iq + (float)NN*vv) / fmaxf(den*iq + (float)NN, 1e-5f);
            outs[((size_t)bt*NN + nn)*AW + g*32 + h2*16 + dd] = f2b(o);
        }
    } else {
        int tix = bx - SBLKS;
        int b = tix / 104;
        int nn0 = (tix % 104) * 2;
        __bf16 (*rows)[2][384] = (__bf16(*)[2][384])(smem);
        float (*invq)[TT][8]  = (float(*)[TT][8])(smem + 18432);
        float (*invk2)[TT][8] = (float(*)[TT][8])(smem + 19200);
        for (int i = tid; i < TT*2*48; i += 256) {
            int t = i / 96, rem = i % 96;
            int nl = rem / 48, g = rem % 48;
            int nn = nn0 + nl;
            bf16x8 v8 = (bf16x8){};
            if (nn < NN) v8 = *reinterpret_cast<const bf16x8*>(qkv + ((size_t)(b*TT+t)*NN + nn)*384 + g*8);
            *reinterpret_cast<bf16x8*>(&rows[t][nl][g*8]) = v8;
        }
        __syncthreads();
        if (tid < 192) {
            int hh = tid & 7, t = (tid >> 3) % TT, nl = tid / 96;
            bf16x8 q0 = *reinterpret_cast<const bf16x8*>(&rows[t][nl][hh*16]);
            bf16x8 q1 = *reinterpret_cast<const bf16x8*>(&rows[t][nl][hh*16+8]);
            bf16x8 k0 = *reinterpret_cast<const bf16x8*>(&rows[t][nl][128+hh*16]);
            bf16x8 k1 = *reinterpret_cast<const bf16x8*>(&rows[t][nl][128+hh*16+8]);
            float sq = 0.f, sk = 0.f;
            #pragma unroll
            for (int m=0;m<8;m++){
                float a0=b2f(q0[m]), a1=b2f(q1[m]); sq += a0*a0 + a1*a1;
                float c0v=b2f(k0[m]), c1=b2f(k1[m]); sk += c0v*c0v + c1*c1;
            }
            invq[nl][t][hh]  = 1.f/fmaxf(sqrtf(sq), 1e-12f);
            invk2[nl][t][hh] = 1.f/fmaxf(sqrtf(sk), 1e-12f);
        }
        __syncthreads();
        int dd = tid & 15, h = (tid >> 4) & 7, nl = tid >> 7;
        int nn = nn0 + nl;
        float kvs_col[16], ksum[16];
        #pragma unroll
        for (int m=0;m<16;m++){ kvs_col[m]=0.f; ksum[m]=0.f; }
        #pragma unroll
        for (int t=0;t<TT;t++){
            float iv = invk2[nl][t][h];
            bf16x8 k0 = *reinterpret_cast<const bf16x8*>(&rows[t][nl][128+h*16]);
            bf16x8 k1 = *reinterpret_cast<const bf16x8*>(&rows[t][nl][128+h*16+8]);
            float vv = b2f(rows[t][nl][256+h*16+dd]);
            float t2 = iv*vv;
            #pragma unroll
            for (int m=0;m<8;m++){
                float km0 = b2f(k0[m]), km1 = b2f(k1[m]);
                kvs_col[m]   += km0*t2;  ksum[m]   += km0*iv;
                kvs_col[m+8] += km1*t2;  ksum[m+8] += km1*iv;
            }
        }
        #pragma unroll
        for (int t=0;t<TT;t++){
            float iq = invq[nl][t][h];
            bf16x8 q0 = *reinterpret_cast<const bf16x8*>(&rows[t][nl][h*16]);
            bf16x8 q1 = *reinterpret_cast<const bf16x8*>(&rows[t][nl][h*16+8]);
            float num = 0.f, den = 0.f;
            #pragma unroll
            for (int m=0;m<8;m++){
                float qm0 = b2f(q0[m]), qm1 = b2f(q1[m]);
                num += qm0*kvs_col[m]  + qm1*kvs_col[m+8];
                den += qm0*ksum[m]     + qm1*ksum[m+8];
            }
            float vv = b2f(rows[t][nl][256+h*16+dd]);
            float o = (num*iq + (float)TT*vv) / fmaxf(den*iq + (float)TT, 1e-5f);
            if (nn < NN)
                outt[((size_t)(b*TT+t)*NN + nn)*AW + h*16 + dd] = f2b(o);
        }
    }
}

extern "C" void kernel_launch(void* const* d_in, const int* in_sizes, int n_in,
                              void* d_out, int out_size, void* d_ws, size_t ws_size,
                              hipStream_t stream)
{
    const float* x     = (const float*)d_in[0];
    const float* graph = (const float*)d_in[1];
    const float* qkv_w = (const float*)d_in[2];
    const float* out_w = (const float*)d_in[3];
    const float* out_b = (const float*)d_in[4];
    const float* pw_w  = (const float*)d_in[5];
    const float* pw_b  = (const float*)d_in[6];
    const float* fc1_w = (const float*)d_in[7];
    const float* fc1_b = (const float*)d_in[8];
    const float* fc2_w = (const float*)d_in[9];
    const float* fc2_b = (const float*)d_in[10];
    const float* ln1g  = (const float*)d_in[11];
    const float* ln1b  = (const float*)d_in[12];
    const float* ln2g  = (const float*)d_in[13];
    const float* ln2b  = (const float*)d_in[14];
    (void)in_sizes; (void)n_in; (void)out_size; (void)ws_size;

    char* ws = (char*)d_ws;
    size_t off = 0;
    __bf16* abuf = (__bf16*)(ws + off); off += (size_t)MROWS*AW*2;
    __bf16* qkvc = (__bf16*)(ws + off); off += (size_t)CROWS*3*DD*2;
    __bf16* gpad = (__bf16*)(ws + off); off += (size_t)TT*NN*KPAD*2;
    __bf16* qkv_wb = (__bf16*)(ws + off); off += (size_t)2*3*DD*DD*2;
    __bf16* wcomb  = (__bf16*)(ws + off); off += (size_t)DD*AW*2;
    __bf16* fc1_wb = (__bf16*)(ws + off); off += (size_t)2*DD*DD*2;
    __bf16* fc2_wb = (__bf16*)(ws + off); off += (size_t)2*DD*DD*2;
    float*  bias_comb = (float*)(ws + off); off += DD*4;

    dim3 blk(256), blk512(512);

    xcopy_kernel<<<dim3(4096), blk, 0, stream>>>(x, abuf);
    prep_misc_kernel<<<dim3(1024), blk, 0, stream>>>(graph, qkv_w, out_w, out_b, pw_w, pw_b,
        fc1_w, fc2_w, gpad, qkv_wb, wcomb, fc1_wb, fc2_wb, bias_comb);
    propagate_kernel<<<dim3(BB*TT, 4), blk, 0, stream>>>(gpad, abuf);

    for (int hop = 0; hop < 2; ++hop) {
        for (int c = 0; c < BB/CHB; ++c) {
            size_t rowoff = (size_t)c*CROWS;
            sgemm_k128<false><<<dim3(170, 3), blk, 0, stream>>>(
                abuf + rowoff*AW + hop*DD, (size_t)AW, qkv_wb + (size_t)hop*3*DD*DD, nullptr,
                qkvc, (size_t)(3*DD), CROWS/16);
            attn_st_kernel<<<dim3(SBLKS + CHB*104), blk, 0, stream>>>(
                qkvc, abuf + rowoff*AW + 256 + hop*256, abuf + rowoff*AW + 384 + hop*256);
        }
    }

    // h = LN1(x + abuf@wcomb^T + bias_comb) -> abuf cols 0:128 (bf16)
    gemm_kernel<3,false><<<dim3(MROWS/256, 1), blk512, 0, stream>>>(
        abuf, (size_t)AW, wcomb, bias_comb, (void*)abuf, (size_t)AW, AW, MROWS,
        abuf, (size_t)AW, ln1g, ln1b);
    // out = LN2(h + relu(h@fc1^T+b1)@fc2^T + b2) -> d_out f32, fused FFN (64-row blocks)
    ffn_kernel<<<dim3(MROWS/64), blk, 0, stream>>>(
        abuf, fc1_wb, fc1_b, fc2_wb, fc2_b, ln2g, ln2b, (float*)d_out);
}

// Round 19
// 723.463 us; speedup vs baseline: 1.1360x; 1.1360x over previous
//
#include <hip/hip_runtime.h>
#include <hip/hip_bf16.h>

#define BB 64
#define TT 12
#define NN 207
#define DD 128
#define HH 8
#define DH 16
#define MROWS (BB*TT*NN)   // 158976 = 621*256 = 2484*64
#define KPAD 224
#define AW 768             // abuf width: [x | xs1 | s0 | t0 | s1 | t1] each 128
#define CHB 32
#define CROWS (CHB*TT*NN)  // 79488 = 4968*16

typedef __bf16 bf16x8 __attribute__((ext_vector_type(8)));
typedef __bf16 bf16x4 __attribute__((ext_vector_type(4)));
typedef float  f32x4  __attribute__((ext_vector_type(4)));
typedef short  s16x4  __attribute__((ext_vector_type(4)));

__device__ inline float  b2f(__bf16 v){ return (float)v; }
__device__ inline __bf16 f2b(float v){ return (__bf16)v; }
__device__ inline bf16x8 ldfrag(const __bf16* p){ return *reinterpret_cast<const bf16x8*>(p); }

__device__ inline void gload_lds16(const __bf16* g, __bf16* l){
    __builtin_amdgcn_global_load_lds(
        (const __attribute__((address_space(1))) void*)(g),
        (__attribute__((address_space(3))) void*)(l), 16, 0, 0);
}
__device__ inline int swz(int r){ return (r ^ (r>>2)) & 3; }
__device__ inline int pkey(int c){ return (c + (c>>2)) & 3; }

// ---------------- x (f32) -> abuf[:,0:128] bf16 ----------------
__global__ __launch_bounds__(256) void xcopy_kernel(const float* __restrict__ x, __bf16* __restrict__ abuf)
{
    int nt = gridDim.x*256;
    for (int gIdx = blockIdx.x*256 + threadIdx.x; gIdx < MROWS*16; gIdx += nt) {
        int row = gIdx >> 4, c8 = (gIdx & 15)*8;
        const float* s = x + (size_t)row*DD + c8;
        f32x4 a = *reinterpret_cast<const f32x4*>(s);
        f32x4 b = *reinterpret_cast<const f32x4*>(s+4);
        bf16x8 r;
        #pragma unroll
        for (int i=0;i<4;i++){ r[i] = f2b(a[i]); r[i+4] = f2b(b[i]); }
        *reinterpret_cast<bf16x8*>(abuf + (size_t)row*AW + c8) = r;
    }
}

// ---------------- misc prep ----------------
__global__ __launch_bounds__(256) void prep_misc_kernel(
    const float* __restrict__ graph, const float* __restrict__ qkv_w,
    const float* __restrict__ out_w, const float* __restrict__ out_b,
    const float* __restrict__ pw_w,  const float* __restrict__ pw_b,
    const float* __restrict__ fc1_w, const float* __restrict__ fc2_w,
    __bf16* __restrict__ gpad, __bf16* __restrict__ qkv_wb, __bf16* __restrict__ wcomb,
    __bf16* __restrict__ fc1_wb, __bf16* __restrict__ fc2_wb, float* __restrict__ bias_comb)
{
    int nt = gridDim.x*256;
    int tid = blockIdx.x*256 + threadIdx.x;
    for (int i = tid; i < TT*NN*KPAD; i += nt) {
        int k = i % KPAD, r = i / KPAD;
        gpad[i] = (k < NN) ? f2b(graph[(size_t)r*NN + k]) : f2b(0.f);
    }
    for (int i = tid; i < 2*3*DD*DD; i += nt) qkv_wb[i] = f2b(qkv_w[i]);
    for (int i = tid; i < DD*AW; i += nt) {
        int c = i / AW, j = i % AW;
        float v;
        if      (j < 128) v = pw_w[c*128 + j];
        else if (j < 256) v = pw_w[128*128 + c*128 + (j-128)];
        else if (j < 512) v = out_w[c*256 + (j-256)];
        else              v = out_w[128*256 + c*256 + (j-512)];
        wcomb[i] = f2b(v);
    }
    for (int i = tid; i < 2*DD*DD; i += nt) fc1_wb[i] = f2b(fc1_w[i]);
    for (int i = tid; i < 2*DD*DD; i += nt) fc2_wb[i] = f2b(fc2_w[i]);
    for (int i = tid; i < DD; i += nt)
        bias_comb[i] = pw_b[i] + pw_b[128+i] + out_b[i] + out_b[128+i];
}

// ---------------- propagate: abuf[:,128:256] = graph[t] @ abuf[:,0:128]  per (b,t) ----------------
__global__ __launch_bounds__(256) void propagate_kernel(const __bf16* __restrict__ gp,
    __bf16* __restrict__ abuf)
{
    int bt   = blockIdx.x;
    int t    = bt % TT;
    int tile = blockIdx.y;
    int lane = threadIdx.x & 63, w = threadIdx.x >> 6;
    int lhi = lane >> 4, llo = lane & 15;
    __shared__ __attribute__((aligned(16))) __bf16 XT[DD][40];
    const __bf16* xbt  = abuf + (size_t)bt*NN*AW;
    const __bf16* grow = gp + (size_t)t*NN*KPAD;
    int rowbase = tile*64 + w*16;
    f32x4 acc[8];
    #pragma unroll
    for (int i=0;i<8;i++) acc[i] = (f32x4){0.f,0.f,0.f,0.f};
    int arow = rowbase + llo; if (arow > NN-1) arow = NN-1;
    for (int k0=0; k0<KPAD; k0+=32) {
        __syncthreads();
        for (int kl = (threadIdx.x>>7); kl < 32; kl += 2) {
            int kk = k0 + kl, c = threadIdx.x & 127;
            __bf16 xb = (kk < NN) ? xbt[(size_t)kk*AW + c] : f2b(0.f);
            XT[c][(((kl>>3) ^ pkey(c))<<3) | (kl&7)] = xb;
        }
        __syncthreads();
        bf16x8 a = ldfrag(grow + (size_t)arow*KPAD + k0 + lhi*8);
        #pragma unroll
        for (int cf=0;cf<8;cf++){
            int row = cf*16+llo;
            bf16x8 b = *reinterpret_cast<const bf16x8*>(&XT[row][(lhi ^ pkey(row))<<3]);
            acc[cf] = __builtin_amdgcn_mfma_f32_16x16x32_bf16(a, b, acc[cf], 0,0,0);
        }
    }
    #pragma unroll
    for (int e=0;e<4;e++){
        int row = rowbase + lhi*4 + e;
        if (row < NN) {
            #pragma unroll
            for (int cf=0;cf<8;cf++)
                abuf[((size_t)bt*NN + row)*AW + DD + cf*16 + llo] = f2b(acc[cf][e]);
        }
    }
}

// ---------------- R7 LDS-staged GEMM (512 thr, 256x128, ring-3, counted vmcnt) ----------------
// MODE 3: out_bf16 = LN(resid + acc + bias)
template<int MODE, bool RELU>
__global__ __launch_bounds__(512) void gemm_kernel(const __bf16* __restrict__ A, size_t lda,
    const __bf16* __restrict__ W, const float* __restrict__ bias,
    void* out, size_t ldc, int K, int mend,
    const __bf16* __restrict__ resid, size_t ldr,
    const float* __restrict__ lng, const float* __restrict__ lnb)
{
    __shared__ __attribute__((aligned(16))) __bf16 lds[3][12288];
    int w = threadIdx.x >> 6, lane = threadIdx.x & 63;
    int lhi = lane >> 4, llo = lane & 15;
    size_t row0 = (size_t)blockIdx.x*256;
    int col0 = blockIdx.y*128;
    int nt = K >> 5;

    int sA0 = (w*2+0)*64 + lane, sA1 = (w*2+1)*64 + lane, sW = w*64 + lane;
    int rA0 = sA0>>2, uA0 = sA0&3, rA1 = sA1>>2, uA1 = sA1&3, rW = sW>>2, uW = sW&3;
    long gr0 = (long)row0 + rA0; if (gr0 >= mend) gr0 = mend-1;
    long gr1 = (long)row0 + rA1; if (gr1 >= mend) gr1 = mend-1;
    const __bf16* gA0 = A + (size_t)gr0*lda + ((uA0 ^ swz(rA0))<<3);
    const __bf16* gA1 = A + (size_t)gr1*lda + ((uA1 ^ swz(rA1))<<3);
    const __bf16* gW  = W + (size_t)(col0 + rW)*K + ((uW ^ swz(rW))<<3);
    __bf16* base0 = &lds[0][0];

    int aoff[2], woff[8];
    #pragma unroll
    for (int rt=0;rt<2;rt++){
        int rl = w*32 + rt*16 + llo;
        aoff[rt] = rl*32 + ((lhi ^ swz(rl))<<3);
    }
    #pragma unroll
    for (int cf=0;cf<8;cf++){
        int wr = cf*16 + llo;
        woff[cf] = 8192 + wr*32 + ((lhi ^ swz(wr))<<3);
    }

    f32x4 acc[2][8];
    #pragma unroll
    for (int i=0;i<2;i++)
        #pragma unroll
        for (int j=0;j<8;j++) acc[i][j] = (f32x4){0.f,0.f,0.f,0.f};

    #define STAGE(buf, tt) { int k0 = (tt)<<5; __bf16* Lw = base0 + (buf)*12288;           \
        gload_lds16(gA0 + k0, Lw + (w*2+0)*512);                                           \
        gload_lds16(gA1 + k0, Lw + (w*2+1)*512);                                           \
        gload_lds16(gW  + k0, Lw + 8192 + w*512); }

    STAGE(0,0); STAGE(1,1); STAGE(2,2);

    int cur = 0;
    for (int t = 0; t < nt; ++t) {
        if (t <= nt-3)      asm volatile("s_waitcnt vmcnt(6)" ::: "memory");
        else if (t == nt-2) asm volatile("s_waitcnt vmcnt(3)" ::: "memory");
        else                asm volatile("s_waitcnt vmcnt(0)" ::: "memory");
        __builtin_amdgcn_s_barrier();
        __builtin_amdgcn_sched_barrier(0);
        const __bf16* Lb = base0 + cur*12288;
        bf16x8 a[2], b[8];
        #pragma unroll
        for (int rt=0;rt<2;rt++) a[rt] = *reinterpret_cast<const bf16x8*>(&Lb[aoff[rt]]);
        #pragma unroll
        for (int cf=0;cf<8;cf++)  b[cf] = *reinterpret_cast<const bf16x8*>(&Lb[woff[cf]]);
        asm volatile("s_waitcnt lgkmcnt(0)" ::: "memory");
        __builtin_amdgcn_sched_barrier(0);
        __builtin_amdgcn_s_barrier();
        if (t+3 < nt) STAGE(cur, t+3);
        #pragma unroll
        for (int rt=0;rt<2;rt++)
            #pragma unroll
            for (int cf=0;cf<8;cf++)
                acc[rt][cf] = __builtin_amdgcn_mfma_f32_16x16x32_bf16(a[rt], b[cf], acc[rt][cf], 0,0,0);
        cur = (cur == 2) ? 0 : cur + 1;
    }
    #undef STAGE

    float bv[8];
    #pragma unroll
    for (int cf=0;cf<8;cf++) bv[cf] = bias ? bias[col0 + cf*16 + llo] : 0.f;

    if (MODE == 0) {
        #pragma unroll
        for (int rt=0;rt<2;rt++) {
            #pragma unroll
            for (int e=0;e<4;e++) {
                size_t row = row0 + (size_t)w*32 + rt*16 + lhi*4 + e;
                if ((long)row >= mend) continue;
                #pragma unroll
                for (int cf=0;cf<8;cf++) {
                    float v = acc[rt][cf][e] + bv[cf];
                    if (RELU) v = fmaxf(v, 0.f);
                    ((__bf16*)out)[row*ldc + col0 + cf*16 + llo] = f2b(v);
                }
            }
        }
    } else {
        float g8[8], b8[8];
        #pragma unroll
        for (int cf=0;cf<8;cf++){ int c = cf*16 + llo; g8[cf] = lng[c]; b8[cf] = lnb[c]; }
        #pragma unroll
        for (int rt=0;rt<2;rt++) {
            #pragma unroll
            for (int e=0;e<4;e++) {
                size_t row = row0 + (size_t)w*32 + rt*16 + lhi*4 + e;
                if ((long)row >= mend) continue;
                float vals[8], s = 0.f, ss = 0.f;
                #pragma unroll
                for (int cf=0;cf<8;cf++) {
                    int c = cf*16 + llo;
                    float r = b2f(resid[row*ldr + c]);
                    float v = acc[rt][cf][e] + bv[cf] + r;
                    vals[cf] = v; s += v; ss += v*v;
                }
                #pragma unroll
                for (int o=1;o<16;o<<=1){ s += __shfl_xor(s,o,64); ss += __shfl_xor(ss,o,64); }
                float mean = s * (1.f/DD);
                float var  = ss * (1.f/DD) - mean*mean;
                float rs   = rsqrtf(var + 1e-5f);
                #pragma unroll
                for (int cf=0;cf<8;cf++) {
                    float v = (vals[cf]-mean)*rs*g8[cf] + b8[cf];
                    ((__bf16*)out)[row*ldc + cf*16 + llo] = f2b(v);
                }
            }
        }
    }
}

// ---------------- streaming K=128 GEMM: W in VGPRs, wave-private LDS ring-3, no barriers ----
template<bool RELU>
__global__ __launch_bounds__(256) void sgemm_k128(const __bf16* __restrict__ A, size_t lda,
    const __bf16* __restrict__ W, const float* __restrict__ bias,
    __bf16* __restrict__ out, size_t ldc, int ngroups)
{
    __shared__ __attribute__((aligned(16))) __bf16 lds[12][2048];
    int w = threadIdx.x >> 6, lane = threadIdx.x & 63;
    int lhi = lane >> 4, llo = lane & 15;
    int col0 = blockIdx.y*128;

    bf16x8 wf[4][8];
    #pragma unroll
    for (int ks=0;ks<4;ks++)
        #pragma unroll
        for (int cf=0;cf<8;cf++)
            wf[ks][cf] = ldfrag(W + (size_t)(col0 + cf*16 + llo)*128 + ks*32 + lhi*8);

    f32x4 bvv[8];
    #pragma unroll
    for (int cf=0;cf<8;cf++){
        if (bias) bvv[cf] = *reinterpret_cast<const f32x4*>(bias + col0 + cf*16 + lhi*4);
        else      bvv[cf] = (f32x4){0.f,0.f,0.f,0.f};
    }

    size_t gsrc[4];
    #pragma unroll
    for (int j=0;j<4;j++){
        int r = j*4 + lhi;
        int u = llo ^ r;
        gsrc[j] = (size_t)r*lda + (size_t)u*8;
    }
    int aoff[4];
    #pragma unroll
    for (int ks=0;ks<4;ks++) aoff[ks] = llo*128 + (((ks<<2)|lhi) ^ llo)*8;

    int gw = blockIdx.x*4 + w, stride = gridDim.x*4;
    int n = (gw < ngroups) ? ((ngroups-1-gw)/stride + 1) : 0;
    __bf16* slab0 = &lds[w*3][0];

    #define SSTAGE(i) { size_t rbase = (size_t)(gw + (size_t)(i)*stride)*16*lda;           \
        __bf16* L = slab0 + ((i)%3)*2048;                                                  \
        gload_lds16(A + rbase + gsrc[0], L);                                               \
        gload_lds16(A + rbase + gsrc[1], L + 512);                                         \
        gload_lds16(A + rbase + gsrc[2], L + 1024);                                        \
        gload_lds16(A + rbase + gsrc[3], L + 1536); }

    if (n > 0) SSTAGE(0);
    if (n > 1) SSTAGE(1);

    for (int i = 0; i < n; ++i) {
        int kept = ((i+1 < n) ? 4 : 0) + ((i >= 2) ? 16 : i*8);
        if      (kept >= 20) asm volatile("s_waitcnt vmcnt(20)" ::: "memory");
        else if (kept == 16) asm volatile("s_waitcnt vmcnt(16)" ::: "memory");
        else if (kept == 12) asm volatile("s_waitcnt vmcnt(12)" ::: "memory");
        else if (kept == 8)  asm volatile("s_waitcnt vmcnt(8)"  ::: "memory");
        else if (kept == 4)  asm volatile("s_waitcnt vmcnt(4)"  ::: "memory");
        else                 asm volatile("s_waitcnt vmcnt(0)"  ::: "memory");

        const __bf16* Ls = slab0 + (i%3)*2048;
        bf16x8 a[4];
        #pragma unroll
        for (int ks=0;ks<4;ks++) a[ks] = *reinterpret_cast<const bf16x8*>(&Ls[aoff[ks]]);

        if (i+2 < n) SSTAGE(i+2);

        f32x4 acc[8];
        #pragma unroll
        for (int cf=0;cf<8;cf++) acc[cf] = (f32x4){0.f,0.f,0.f,0.f};
        #pragma unroll
        for (int ks=0;ks<4;ks++)
            #pragma unroll
            for (int cf=0;cf<8;cf++)
                acc[cf] = __builtin_amdgcn_mfma_f32_16x16x32_bf16(wf[ks][cf], a[ks], acc[cf], 0,0,0);

        size_t grow = (size_t)(gw + (size_t)i*stride)*16 + llo;
        #pragma unroll
        for (int cf=0;cf<8;cf++){
            bf16x4 o;
            #pragma unroll
            for (int e=0;e<4;e++){
                float v = acc[cf][e] + bvv[cf][e];
                if (RELU) v = fmaxf(v, 0.f);
                o[e] = f2b(v);
            }
            *reinterpret_cast<bf16x4*>(out + grow*ldc + col0 + cf*16 + lhi*4) = o;
        }
    }
    #undef SSTAGE
}

// ---------------- fused FFN (64-row blocks, ring-2 prologue-staged) ----------
__global__ __launch_bounds__(256) void ffn_kernel(const __bf16* __restrict__ h,
    const __bf16* __restrict__ w1, const float* __restrict__ b1,
    const __bf16* __restrict__ w2, const float* __restrict__ b2,
    const float* __restrict__ lng, const float* __restrict__ lnb,
    float* __restrict__ dout)
{
    __shared__ __attribute__((aligned(16))) __bf16 hring[2][4096];
    __shared__ __attribute__((aligned(16))) __bf16 f1b[8192];
    __shared__ float fl2[2][32][4][2];
    int w = threadIdx.x >> 6, lane = threadIdx.x & 63;
    int lhi = lane >> 4, llo = lane & 15;
    size_t row0 = (size_t)blockIdx.x * 64;

    size_t gsrc[2]; int ldst[2];
    #pragma unroll
    for (int j=0;j<2;j++){
        int i = w*64 + lane + 256*j;
        int r = i >> 4, u = i & 15;
        gsrc[j] = (size_t)r*AW + ((u ^ (r & 15)) << 3);
        ldst[j] = (w*64 + 256*j) * 8;
    }
    #define FSTAGE(slot, g) { const __bf16* src = h + (row0 + (size_t)(g)*32)*AW;          \
        gload_lds16(src + gsrc[0], &hring[slot][0] + ldst[0]);                             \
        gload_lds16(src + gsrc[1], &hring[slot][0] + ldst[1]); }

    f32x4 b1v[4], b2v[2], gv[2], bt2[2];
    #pragma unroll
    for (int c4=0;c4<4;c4++) b1v[c4] = *reinterpret_cast<const f32x4*>(b1 + w*64 + c4*16 + lhi*4);
    #pragma unroll
    for (int c2=0;c2<2;c2++){
        b2v[c2] = *reinterpret_cast<const f32x4*>(b2  + w*32 + c2*16 + lhi*4);
        gv[c2]  = *reinterpret_cast<const f32x4*>(lng + w*32 + c2*16 + lhi*4);
        bt2[c2] = *reinterpret_cast<const f32x4*>(lnb + w*32 + c2*16 + lhi*4);
    }

    FSTAGE(0,0); FSTAGE(1,1);

    for (int g = 0; g < 2; ++g) {
        if (g == 0) asm volatile("s_waitcnt vmcnt(2)" ::: "memory");
        else        asm volatile("s_waitcnt vmcnt(0)" ::: "memory");
        __builtin_amdgcn_s_barrier();
        __builtin_amdgcn_sched_barrier(0);
        const __bf16* Hs = &hring[g][0];

        bf16x8 hb[2][4];
        bf16x4 hres[2][2];
        #pragma unroll
        for (int rf=0;rf<2;rf++){
            int r = rf*16 + llo;
            #pragma unroll
            for (int ks=0;ks<4;ks++)
                hb[rf][ks] = *reinterpret_cast<const bf16x8*>(Hs + r*128 + (((ks*4+lhi) ^ llo) << 3));
            #pragma unroll
            for (int cf=0;cf<2;cf++){
                int unit = w*4 + cf*2 + (lhi>>1);
                hres[cf][rf] = *reinterpret_cast<const bf16x4*>(Hs + r*128 + ((unit ^ llo) << 3) + (lhi & 1)*4);
            }
        }
        asm volatile("s_waitcnt lgkmcnt(0)" ::: "memory");
        __builtin_amdgcn_sched_barrier(0);

        f32x4 acc1[4][2];
        #pragma unroll
        for (int i=0;i<4;i++){ acc1[i][0] = (f32x4){0,0,0,0}; acc1[i][1] = (f32x4){0,0,0,0}; }
        #pragma unroll
        for (int ks=0;ks<4;ks++){
            #pragma unroll
            for (int cf2=0;cf2<4;cf2++){
                bf16x8 wfr = ldfrag(w1 + (size_t)(w*64 + cf2*16 + llo)*128 + ks*32 + lhi*8);
                #pragma unroll
                for (int rf=0;rf<2;rf++)
                    acc1[cf2][rf] = __builtin_amdgcn_mfma_f32_16x16x32_bf16(wfr, hb[rf][ks], acc1[cf2][rf], 0,0,0);
            }
        }
        #pragma unroll
        for (int rf=0;rf<2;rf++){
            int r = rf*16 + llo;
            #pragma unroll
            for (int cf2=0;cf2<4;cf2++){
                bf16x4 o;
                #pragma unroll
                for (int e=0;e<4;e++) o[e] = f2b(fmaxf(acc1[cf2][rf][e] + b1v[cf2][e], 0.f));
                int unit = w*8 + cf2*2 + (lhi>>1);
                *reinterpret_cast<bf16x4*>(&f1b[r*256 + ((unit ^ r) << 3) + (lhi&1)*4]) = o;
            }
        }
        asm volatile("s_waitcnt lgkmcnt(0)" ::: "memory");
        __builtin_amdgcn_sched_barrier(0);
        __builtin_amdgcn_s_barrier();

        f32x4 acc2[2][2];
        acc2[0][0]=(f32x4){0,0,0,0}; acc2[0][1]=(f32x4){0,0,0,0};
        acc2[1][0]=(f32x4){0,0,0,0}; acc2[1][1]=(f32x4){0,0,0,0};
        #pragma unroll
        for (int ks2=0;ks2<8;ks2++){
            bf16x8 fb[2];
            #pragma unroll
            for (int rf=0;rf<2;rf++){
                int r = rf*16 + llo;
                fb[rf] = *reinterpret_cast<const bf16x8*>(&f1b[r*256 + (((ks2*4+lhi) ^ r) << 3)]);
            }
            #pragma unroll
            for (int cf=0;cf<2;cf++){
                bf16x8 wfr = ldfrag(w2 + (size_t)(w*32 + cf*16 + llo)*256 + ks2*32 + lhi*8);
                #pragma unroll
                for (int rf=0;rf<2;rf++)
                    acc2[cf][rf] = __builtin_amdgcn_mfma_f32_16x16x32_bf16(wfr, fb[rf], acc2[cf][rf], 0,0,0);
            }
        }

        float vals[2][2][4]; float s[2] = {0.f,0.f}, ss[2] = {0.f,0.f};
        #pragma unroll
        for (int rf=0;rf<2;rf++)
            #pragma unroll
            for (int cf=0;cf<2;cf++)
                #pragma unroll
                for (int e=0;e<4;e++){
                    float v = acc2[cf][rf][e] + b2v[cf][e] + b2f(hres[cf][rf][e]);
                    vals[rf][cf][e] = v; s[rf] += v; ss[rf] += v*v;
                }
        #pragma unroll
        for (int rf=0;rf<2;rf++){
            s[rf]  += __shfl_xor(s[rf],16,64);  s[rf]  += __shfl_xor(s[rf],32,64);
            ss[rf] += __shfl_xor(ss[rf],16,64); ss[rf] += __shfl_xor(ss[rf],32,64);
            if (lhi == 0){ fl2[g][rf*16+llo][w][0] = s[rf]; fl2[g][rf*16+llo][w][1] = ss[rf]; }
        }
        asm volatile("s_waitcnt lgkmcnt(0)" ::: "memory");
        __builtin_amdgcn_s_barrier();
        #pragma unroll
        for (int rf=0;rf<2;rf++){
            int r = rf*16 + llo;
            float S  = fl2[g][r][0][0]+fl2[g][r][1][0]+fl2[g][r][2][0]+fl2[g][r][3][0];
            float SS = fl2[g][r][0][1]+fl2[g][r][1][1]+fl2[g][r][2][1]+fl2[g][r][3][1];
            float mean = S*(1.f/DD), var = SS*(1.f/DD)-mean*mean, rs = rsqrtf(var+1e-5f);
            size_t grow = row0 + (size_t)g*32 + r;
            #pragma unroll
            for (int cf=0;cf<2;cf++){
                f32x4 o;
                #pragma unroll
                for (int e=0;e<4;e++) o[e] = (vals[rf][cf][e]-mean)*rs*gv[cf][e] + bt2[cf][e];
                *reinterpret_cast<f32x4*>(dout + grow*DD + w*32 + cf*16 + lhi*4) = o;
            }
        }
        if (g == 0) __builtin_amdgcn_s_barrier();
    }
    #undef FSTAGE
}

// ---------------- merged spatial+temporal linear attention ----------------
// Spatial branch: MFMA formulation.
//   kvs[m][dd] = sum_n khat[n][m]*v[n][dd]  via mfma_16x16x32 (A=khatT, B=vT) per 32-n chunk
//   ksum[m]    = sum_n khat[n][m]           via mfma with B=ones
//   num = Q·kvs, den_raw = Q·ksum           via mfma_16x16x16bf16_1k (b-frags held in-lane)
#define ACH 32
#define SBLKS (CHB*TT*4)
__global__ __launch_bounds__(256) void attn_st_kernel(const __bf16* __restrict__ qkv,
    __bf16* __restrict__ outs, __bf16* __restrict__ outt)
{
    __shared__ __attribute__((aligned(16))) char smem[49664];
    int tid = threadIdx.x;
    int bx = blockIdx.x;

    if (bx < SBLKS) {
        int bt = bx >> 2, g = bx & 3;
        const __bf16* base = qkv + (size_t)bt*NN*384 + g*32;
        __bf16 (*qbuf)[40] = (__bf16(*)[40])(smem);                 // 224x40 @0
        __bf16 (*vbuf)[40] = (__bf16(*)[40])(smem + 17920);         // 224x40
        __bf16 (*kbuf)[40] = (__bf16(*)[40])(smem + 35840);         // 32x40
        __bf16 (*khT)[40]  = (__bf16(*)[40])(smem + 38400);         // 32x40  khatT[m][n]
        __bf16 (*vT)[40]   = (__bf16(*)[40])(smem + 40960);         // 32x40  vT[dd][n]
        float  (*iqt)[224] = (float(*)[224])(smem + 43520);         // [2][224] q inv-norms
        float*  kvp        = (float*)(smem + 45312);                // [4][16][16]
        float*  ksp        = (float*)(smem + 49408);                // [4][16]
        int wave = tid >> 6, lane = tid & 63;
        int lhi = lane >> 4, llo = lane & 15;
        int h = wave >> 1;                    // head of pair for this wave
        int r8 = tid >> 3, i8 = tid & 7;      // norm/transpose assignment
        int thead = i8 >> 2, tm4 = (i8 & 3) * 4;

        f32x4 kvs = (f32x4){0,0,0,0}, ksm = (f32x4){0,0,0,0};
        bf16x8 ones8;
        #pragma unroll
        for (int j=0;j<8;j++) ones8[j] = f2b(1.0f);

        for (int c = 0; c < 7; ++c) {
            int c0 = c*32;
            __syncthreads();   // protect khT/vT/kbuf from prior chunk's readers
            for (int i = tid; i < ACH*12; i += 256) {
                int r = i/12, u = i%12, seg = u>>2, uu = u&3;
                int nn = c0 + r;
                bf16x8 v8 = (bf16x8){};
                if (nn < NN) v8 = *reinterpret_cast<const bf16x8*>(base + (size_t)nn*384 + seg*128 + uu*8);
                if      (seg == 0) *reinterpret_cast<bf16x8*>(&qbuf[nn][uu*8]) = v8;
                else if (seg == 1) *reinterpret_cast<bf16x8*>(&kbuf[r][uu*8])  = v8;
                else               *reinterpret_cast<bf16x8*>(&vbuf[nn][uu*8]) = v8;
            }
            __syncthreads();
            {   // norms + transposed writes: thread (r8, i8): row r8, head thead, dims tm4..+3
                int r = r8, nn = c0 + r8;
                float kv[4], vv[4];
                float sk = 0.f, sq = 0.f;
                #pragma unroll
                for (int j=0;j<4;j++){
                    kv[j] = b2f(kbuf[r][thead*16 + tm4 + j]); sk += kv[j]*kv[j];
                    float qv = b2f(qbuf[nn][thead*16 + tm4 + j]); sq += qv*qv;
                    vv[j] = b2f(vbuf[nn][thead*16 + tm4 + j]);
                }
                sk += __shfl_xor(sk,1,64); sk += __shfl_xor(sk,2,64);
                sq += __shfl_xor(sq,1,64); sq += __shfl_xor(sq,2,64);
                float iv = 1.f/fmaxf(sqrtf(sk), 1e-12f);
                #pragma unroll
                for (int j=0;j<4;j++){
                    khT[thead*16 + tm4 + j][r] = f2b(kv[j]*iv);
                    vT [thead*16 + tm4 + j][r] = f2b(vv[j]);
                }
                if ((i8 & 3) == 0) iqt[thead][nn] = 1.f/fmaxf(sqrtf(sq), 1e-12f);
            }
            __syncthreads();
            if ((c & 1) == (wave & 1)) {
                bf16x8 a = *reinterpret_cast<const bf16x8*>(&khT[h*16 + llo][lhi*8]);
                bf16x8 b = *reinterpret_cast<const bf16x8*>(&vT [h*16 + llo][lhi*8]);
                kvs = __builtin_amdgcn_mfma_f32_16x16x32_bf16(a, b, kvs, 0,0,0);
                ksm = __builtin_amdgcn_mfma_f32_16x16x32_bf16(a, ones8, ksm, 0,0,0);
            }
        }
        // combine wave pairs (0<->1 head0, 2<->3 head1)
        #pragma unroll
        for (int e=0;e<4;e++) kvp[wave*256 + (lhi*4+e)*16 + llo] = kvs[e];
        if (llo == 0){
            #pragma unroll
            for (int e=0;e<4;e++) ksp[wave*16 + lhi*4 + e] = ksm[e];
        }
        __syncthreads();
        int pw = wave ^ 1;
        #pragma unroll
        for (int e=0;e<4;e++){
            kvs[e] += kvp[pw*256 + (lhi*4+e)*16 + llo];
            ksm[e] += ksp[pw*16 + lhi*4 + e];
        }
        // pack b-frags in-lane: lane (llo=dd, lhi) holds kvs[m=lhi*4+e][dd] — exactly B'[dd][m]
        union { bf16x4 b; s16x4 s; } bk, bs;
        #pragma unroll
        for (int e=0;e<4;e++){ bk.b[e] = f2b(kvs[e]); bs.b[e] = f2b(ksm[e]); }
        // pass 2: num/den per 16-row tile via K=16 MFMA
        for (int t = (wave & 1); t < 13; t += 2) {
            int n0 = t*16;
            union { bf16x4 b; s16x4 s; } aq;
            aq.b = *reinterpret_cast<const bf16x4*>(&qbuf[n0 + llo][h*16 + lhi*4]);
            f32x4 num = __builtin_amdgcn_mfma_f32_16x16x16bf16_1k(aq.s, bk.s, (f32x4){0,0,0,0}, 0,0,0);
            f32x4 den = __builtin_amdgcn_mfma_f32_16x16x16bf16_1k(aq.s, bs.s, (f32x4){0,0,0,0}, 0,0,0);
            #pragma unroll
            for (int e=0;e<4;e++){
                int n = n0 + lhi*4 + e;
                if (n >= NN) continue;
                float iq = iqt[h][n];
                float vv = b2f(vbuf[n][h*16 + llo]);
                float o = (num[e]*iq + (float)NN*vv) / fmaxf(den[e]*iq + (float)NN, 1e-5f);
                outs[((size_t)bt*NN + n)*AW + g*32 + h*16 + llo] = f2b(o);
            }
        }
    } else {
        int tix = bx - SBLKS;
        int b = tix / 104;
        int nn0 = (tix % 104) * 2;
        __bf16 (*rows)[2][384] = (__bf16(*)[2][384])(smem);
        float (*invq)[TT][8]  = (float(*)[TT][8])(smem + 18432);
        float (*invk2)[TT][8] = (float(*)[TT][8])(smem + 19200);
        for (int i = tid; i < TT*2*48; i += 256) {
            int t = i / 96, rem = i % 96;
            int nl = rem / 48, g = rem % 48;
            int nn = nn0 + nl;
            bf16x8 v8 = (bf16x8){};
            if (nn < NN) v8 = *reinterpret_cast<const bf16x8*>(qkv + ((size_t)(b*TT+t)*NN + nn)*384 + g*8);
            *reinterpret_cast<bf16x8*>(&rows[t][nl][g*8]) = v8;
        }
        __syncthreads();
        if (tid < 192) {
            int hh = tid & 7, t = (tid >> 3) % TT, nl = tid / 96;
            bf16x8 q0 = *reinterpret_cast<const bf16x8*>(&rows[t][nl][hh*16]);
            bf16x8 q1 = *reinterpret_cast<const bf16x8*>(&rows[t][nl][hh*16+8]);
            bf16x8 k0 = *reinterpret_cast<const bf16x8*>(&rows[t][nl][128+hh*16]);
            bf16x8 k1 = *reinterpret_cast<const bf16x8*>(&rows[t][nl][128+hh*16+8]);
            float sq = 0.f, sk = 0.f;
            #pragma unroll
            for (int m=0;m<8;m++){
                float a0=b2f(q0[m]), a1=b2f(q1[m]); sq += a0*a0 + a1*a1;
                float c0v=b2f(k0[m]), c1=b2f(k1[m]); sk += c0v*c0v + c1*c1;
            }
            invq[nl][t][hh]  = 1.f/fmaxf(sqrtf(sq), 1e-12f);
            invk2[nl][t][hh] = 1.f/fmaxf(sqrtf(sk), 1e-12f);
        }
        __syncthreads();
        int dd = tid & 15, h = (tid >> 4) & 7, nl = tid >> 7;
        int nn = nn0 + nl;
        float kvs_col[16], ksum[16];
        #pragma unroll
        for (int m=0;m<16;m++){ kvs_col[m]=0.f; ksum[m]=0.f; }
        #pragma unroll
        for (int t=0;t<TT;t++){
            float iv = invk2[nl][t][h];
            bf16x8 k0 = *reinterpret_cast<const bf16x8*>(&rows[t][nl][128+h*16]);
            bf16x8 k1 = *reinterpret_cast<const bf16x8*>(&rows[t][nl][128+h*16+8]);
            float vv = b2f(rows[t][nl][256+h*16+dd]);
            float t2 = iv*vv;
            #pragma unroll
            for (int m=0;m<8;m++){
                float km0 = b2f(k0[m]), km1 = b2f(k1[m]);
                kvs_col[m]   += km0*t2;  ksum[m]   += km0*iv;
                kvs_col[m+8] += km1*t2;  ksum[m+8] += km1*iv;
            }
        }
        #pragma unroll
        for (int t=0;t<TT;t++){
            float iq = invq[nl][t][h];
            bf16x8 q0 = *reinterpret_cast<const bf16x8*>(&rows[t][nl][h*16]);
            bf16x8 q1 = *reinterpret_cast<const bf16x8*>(&rows[t][nl][h*16+8]);
            float num = 0.f, den = 0.f;
            #pragma unroll
            for (int m=0;m<8;m++){
                float qm0 = b2f(q0[m]), qm1 = b2f(q1[m]);
                num += qm0*kvs_col[m]  + qm1*kvs_col[m+8];
                den += qm0*ksum[m]     + qm1*ksum[m+8];
            }
            float vv = b2f(rows[t][nl][256+h*16+dd]);
            float o = (num*iq + (float)TT*vv) / fmaxf(den*iq + (float)TT, 1e-5f);
            if (nn < NN)
                outt[((size_t)(b*TT+t)*NN + nn)*AW + h*16 + dd] = f2b(o);
        }
    }
}

extern "C" void kernel_launch(void* const* d_in, const int* in_sizes, int n_in,
                              void* d_out, int out_size, void* d_ws, size_t ws_size,
                              hipStream_t stream)
{
    const float* x     = (const float*)d_in[0];
    const float* graph = (const float*)d_in[1];
    const float* qkv_w = (const float*)d_in[2];
    const float* out_w = (const float*)d_in[3];
    const float* out_b = (const float*)d_in[4];
    const float* pw_w  = (const float*)d_in[5];
    const float* pw_b  = (const float*)d_in[6];
    const float* fc1_w = (const float*)d_in[7];
    const float* fc1_b = (const float*)d_in[8];
    const float* fc2_w = (const float*)d_in[9];
    const float* fc2_b = (const float*)d_in[10];
    const float* ln1g  = (const float*)d_in[11];
    const float* ln1b  = (const float*)d_in[12];
    const float* ln2g  = (const float*)d_in[13];
    const float* ln2b  = (const float*)d_in[14];
    (void)in_sizes; (void)n_in; (void)out_size; (void)ws_size;

    char* ws = (char*)d_ws;
    size_t off = 0;
    __bf16* abuf = (__bf16*)(ws + off); off += (size_t)MROWS*AW*2;
    __bf16* qkvc = (__bf16*)(ws + off); off += (size_t)CROWS*3*DD*2;
    __bf16* gpad = (__bf16*)(ws + off); off += (size_t)TT*NN*KPAD*2;
    __bf16* qkv_wb = (__bf16*)(ws + off); off += (size_t)2*3*DD*DD*2;
    __bf16* wcomb  = (__bf16*)(ws + off); off += (size_t)DD*AW*2;
    __bf16* fc1_wb = (__bf16*)(ws + off); off += (size_t)2*DD*DD*2;
    __bf16* fc2_wb = (__bf16*)(ws + off); off += (size_t)2*DD*DD*2;
    float*  bias_comb = (float*)(ws + off); off += DD*4;

    dim3 blk(256), blk512(512);

    xcopy_kernel<<<dim3(4096), blk, 0, stream>>>(x, abuf);
    prep_misc_kernel<<<dim3(1024), blk, 0, stream>>>(graph, qkv_w, out_w, out_b, pw_w, pw_b,
        fc1_w, fc2_w, gpad, qkv_wb, wcomb, fc1_wb, fc2_wb, bias_comb);
    propagate_kernel<<<dim3(BB*TT, 4), blk, 0, stream>>>(gpad, abuf);

    for (int hop = 0; hop < 2; ++hop) {
        for (int c = 0; c < BB/CHB; ++c) {
            size_t rowoff = (size_t)c*CROWS;
            sgemm_k128<false><<<dim3(170, 3), blk, 0, stream>>>(
                abuf + rowoff*AW + hop*DD, (size_t)AW, qkv_wb + (size_t)hop*3*DD*DD, nullptr,
                qkvc, (size_t)(3*DD), CROWS/16);
            attn_st_kernel<<<dim3(SBLKS + CHB*104), blk, 0, stream>>>(
                qkvc, abuf + rowoff*AW + 256 + hop*256, abuf + rowoff*AW + 384 + hop*256);
        }
    }

    // h = LN1(x + abuf@wcomb^T + bias_comb) -> abuf cols 0:128 (bf16)
    gemm_kernel<3,false><<<dim3(MROWS/256, 1), blk512, 0, stream>>>(
        abuf, (size_t)AW, wcomb, bias_comb, (void*)abuf, (size_t)AW, AW, MROWS,
        abuf, (size_t)AW, ln1g, ln1b);
    // out = LN2(h + relu(h@fc1^T+b1)@fc2^T + b2) -> d_out f32, fused FFN (64-row blocks)
    ffn_kernel<<<dim3(MROWS/64), blk, 0, stream>>>(
        abuf, fc1_wb, fc1_b, fc2_wb, fc2_b, ln2g, ln2b, (float*)d_out);
}

// Round 20
// 716.110 us; speedup vs baseline: 1.1477x; 1.0103x over previous
//
#include <hip/hip_runtime.h>
#include <hip/hip_bf16.h>

#define BB 64
#define TT 12
#define NN 207
#define DD 128
#define HH 8
#define DH 16
#define MROWS (BB*TT*NN)   // 158976 = 621*256 = 2484*64
#define KPAD 224
#define AW 768             // abuf width: [x | xs1 | s0 | t0 | s1 | t1] each 128
#define CHB 32
#define CROWS (CHB*TT*NN)  // 79488 = 4968*16

typedef __bf16 bf16x8 __attribute__((ext_vector_type(8)));
typedef __bf16 bf16x4 __attribute__((ext_vector_type(4)));
typedef float  f32x4  __attribute__((ext_vector_type(4)));
typedef short  s16x4  __attribute__((ext_vector_type(4)));

__device__ inline float  b2f(__bf16 v){ return (float)v; }
__device__ inline __bf16 f2b(float v){ return (__bf16)v; }
__device__ inline bf16x8 ldfrag(const __bf16* p){ return *reinterpret_cast<const bf16x8*>(p); }

__device__ inline void gload_lds16(const __bf16* g, __bf16* l){
    __builtin_amdgcn_global_load_lds(
        (const __attribute__((address_space(1))) void*)(g),
        (__attribute__((address_space(3))) void*)(l), 16, 0, 0);
}
__device__ inline int swz(int r){ return (r ^ (r>>2)) & 3; }
__device__ inline int pkey(int c){ return (c + (c>>2)) & 3; }

// ---------------- x (f32) -> abuf[:,0:128] bf16 ----------------
__global__ __launch_bounds__(256) void xcopy_kernel(const float* __restrict__ x, __bf16* __restrict__ abuf)
{
    int nt = gridDim.x*256;
    for (int gIdx = blockIdx.x*256 + threadIdx.x; gIdx < MROWS*16; gIdx += nt) {
        int row = gIdx >> 4, c8 = (gIdx & 15)*8;
        const float* s = x + (size_t)row*DD + c8;
        f32x4 a = *reinterpret_cast<const f32x4*>(s);
        f32x4 b = *reinterpret_cast<const f32x4*>(s+4);
        bf16x8 r;
        #pragma unroll
        for (int i=0;i<4;i++){ r[i] = f2b(a[i]); r[i+4] = f2b(b[i]); }
        *reinterpret_cast<bf16x8*>(abuf + (size_t)row*AW + c8) = r;
    }
}

// ---------------- misc prep ----------------
__global__ __launch_bounds__(256) void prep_misc_kernel(
    const float* __restrict__ graph, const float* __restrict__ qkv_w,
    const float* __restrict__ out_w, const float* __restrict__ out_b,
    const float* __restrict__ pw_w,  const float* __restrict__ pw_b,
    const float* __restrict__ fc1_w, const float* __restrict__ fc2_w,
    __bf16* __restrict__ gpad, __bf16* __restrict__ qkv_wb, __bf16* __restrict__ wcomb,
    __bf16* __restrict__ fc1_wb, __bf16* __restrict__ fc2_wb, float* __restrict__ bias_comb)
{
    int nt = gridDim.x*256;
    int tid = blockIdx.x*256 + threadIdx.x;
    for (int i = tid; i < TT*NN*KPAD; i += nt) {
        int k = i % KPAD, r = i / KPAD;
        gpad[i] = (k < NN) ? f2b(graph[(size_t)r*NN + k]) : f2b(0.f);
    }
    for (int i = tid; i < 2*3*DD*DD; i += nt) qkv_wb[i] = f2b(qkv_w[i]);
    for (int i = tid; i < DD*AW; i += nt) {
        int c = i / AW, j = i % AW;
        float v;
        if      (j < 128) v = pw_w[c*128 + j];
        else if (j < 256) v = pw_w[128*128 + c*128 + (j-128)];
        else if (j < 512) v = out_w[c*256 + (j-256)];
        else              v = out_w[128*256 + c*256 + (j-512)];
        wcomb[i] = f2b(v);
    }
    for (int i = tid; i < 2*DD*DD; i += nt) fc1_wb[i] = f2b(fc1_w[i]);
    for (int i = tid; i < 2*DD*DD; i += nt) fc2_wb[i] = f2b(fc2_w[i]);
    for (int i = tid; i < DD; i += nt)
        bias_comb[i] = pw_b[i] + pw_b[128+i] + out_b[i] + out_b[128+i];
}

// ---------------- propagate: abuf[:,128:256] = graph[t] @ abuf[:,0:128]  per (b,t) ----------------
__global__ __launch_bounds__(256) void propagate_kernel(const __bf16* __restrict__ gp,
    __bf16* __restrict__ abuf)
{
    int bt   = blockIdx.x;
    int t    = bt % TT;
    int tile = blockIdx.y;
    int lane = threadIdx.x & 63, w = threadIdx.x >> 6;
    int lhi = lane >> 4, llo = lane & 15;
    __shared__ __attribute__((aligned(16))) __bf16 XT[DD][40];
    const __bf16* xbt  = abuf + (size_t)bt*NN*AW;
    const __bf16* grow = gp + (size_t)t*NN*KPAD;
    int rowbase = tile*64 + w*16;
    f32x4 acc[8];
    #pragma unroll
    for (int i=0;i<8;i++) acc[i] = (f32x4){0.f,0.f,0.f,0.f};
    int arow = rowbase + llo; if (arow > NN-1) arow = NN-1;
    for (int k0=0; k0<KPAD; k0+=32) {
        __syncthreads();
        for (int kl = (threadIdx.x>>7); kl < 32; kl += 2) {
            int kk = k0 + kl, c = threadIdx.x & 127;
            __bf16 xb = (kk < NN) ? xbt[(size_t)kk*AW + c] : f2b(0.f);
            XT[c][(((kl>>3) ^ pkey(c))<<3) | (kl&7)] = xb;
        }
        __syncthreads();
        bf16x8 a = ldfrag(grow + (size_t)arow*KPAD + k0 + lhi*8);
        #pragma unroll
        for (int cf=0;cf<8;cf++){
            int row = cf*16+llo;
            bf16x8 b = *reinterpret_cast<const bf16x8*>(&XT[row][(lhi ^ pkey(row))<<3]);
            acc[cf] = __builtin_amdgcn_mfma_f32_16x16x32_bf16(a, b, acc[cf], 0,0,0);
        }
    }
    #pragma unroll
    for (int e=0;e<4;e++){
        int row = rowbase + lhi*4 + e;
        if (row < NN) {
            #pragma unroll
            for (int cf=0;cf<8;cf++)
                abuf[((size_t)bt*NN + row)*AW + DD + cf*16 + llo] = f2b(acc[cf][e]);
        }
    }
}

// ---------------- R7 LDS-staged GEMM (512 thr, 256x128, ring-3, counted vmcnt) ----------------
// MODE 3: out_bf16 = LN(resid + acc + bias)
template<int MODE, bool RELU>
__global__ __launch_bounds__(512) void gemm_kernel(const __bf16* __restrict__ A, size_t lda,
    const __bf16* __restrict__ W, const float* __restrict__ bias,
    void* out, size_t ldc, int K, int mend,
    const __bf16* __restrict__ resid, size_t ldr,
    const float* __restrict__ lng, const float* __restrict__ lnb)
{
    __shared__ __attribute__((aligned(16))) __bf16 lds[3][12288];
    int w = threadIdx.x >> 6, lane = threadIdx.x & 63;
    int lhi = lane >> 4, llo = lane & 15;
    size_t row0 = (size_t)blockIdx.x*256;
    int col0 = blockIdx.y*128;
    int nt = K >> 5;

    int sA0 = (w*2+0)*64 + lane, sA1 = (w*2+1)*64 + lane, sW = w*64 + lane;
    int rA0 = sA0>>2, uA0 = sA0&3, rA1 = sA1>>2, uA1 = sA1&3, rW = sW>>2, uW = sW&3;
    long gr0 = (long)row0 + rA0; if (gr0 >= mend) gr0 = mend-1;
    long gr1 = (long)row0 + rA1; if (gr1 >= mend) gr1 = mend-1;
    const __bf16* gA0 = A + (size_t)gr0*lda + ((uA0 ^ swz(rA0))<<3);
    const __bf16* gA1 = A + (size_t)gr1*lda + ((uA1 ^ swz(rA1))<<3);
    const __bf16* gW  = W + (size_t)(col0 + rW)*K + ((uW ^ swz(rW))<<3);
    __bf16* base0 = &lds[0][0];

    int aoff[2], woff[8];
    #pragma unroll
    for (int rt=0;rt<2;rt++){
        int rl = w*32 + rt*16 + llo;
        aoff[rt] = rl*32 + ((lhi ^ swz(rl))<<3);
    }
    #pragma unroll
    for (int cf=0;cf<8;cf++){
        int wr = cf*16 + llo;
        woff[cf] = 8192 + wr*32 + ((lhi ^ swz(wr))<<3);
    }

    f32x4 acc[2][8];
    #pragma unroll
    for (int i=0;i<2;i++)
        #pragma unroll
        for (int j=0;j<8;j++) acc[i][j] = (f32x4){0.f,0.f,0.f,0.f};

    #define STAGE(buf, tt) { int k0 = (tt)<<5; __bf16* Lw = base0 + (buf)*12288;           \
        gload_lds16(gA0 + k0, Lw + (w*2+0)*512);                                           \
        gload_lds16(gA1 + k0, Lw + (w*2+1)*512);                                           \
        gload_lds16(gW  + k0, Lw + 8192 + w*512); }

    STAGE(0,0); STAGE(1,1); STAGE(2,2);

    int cur = 0;
    for (int t = 0; t < nt; ++t) {
        if (t <= nt-3)      asm volatile("s_waitcnt vmcnt(6)" ::: "memory");
        else if (t == nt-2) asm volatile("s_waitcnt vmcnt(3)" ::: "memory");
        else                asm volatile("s_waitcnt vmcnt(0)" ::: "memory");
        __builtin_amdgcn_s_barrier();
        __builtin_amdgcn_sched_barrier(0);
        const __bf16* Lb = base0 + cur*12288;
        bf16x8 a[2], b[8];
        #pragma unroll
        for (int rt=0;rt<2;rt++) a[rt] = *reinterpret_cast<const bf16x8*>(&Lb[aoff[rt]]);
        #pragma unroll
        for (int cf=0;cf<8;cf++)  b[cf] = *reinterpret_cast<const bf16x8*>(&Lb[woff[cf]]);
        asm volatile("s_waitcnt lgkmcnt(0)" ::: "memory");
        __builtin_amdgcn_sched_barrier(0);
        __builtin_amdgcn_s_barrier();
        if (t+3 < nt) STAGE(cur, t+3);
        #pragma unroll
        for (int rt=0;rt<2;rt++)
            #pragma unroll
            for (int cf=0;cf<8;cf++)
                acc[rt][cf] = __builtin_amdgcn_mfma_f32_16x16x32_bf16(a[rt], b[cf], acc[rt][cf], 0,0,0);
        cur = (cur == 2) ? 0 : cur + 1;
    }
    #undef STAGE

    float bv[8];
    #pragma unroll
    for (int cf=0;cf<8;cf++) bv[cf] = bias ? bias[col0 + cf*16 + llo] : 0.f;

    if (MODE == 0) {
        #pragma unroll
        for (int rt=0;rt<2;rt++) {
            #pragma unroll
            for (int e=0;e<4;e++) {
                size_t row = row0 + (size_t)w*32 + rt*16 + lhi*4 + e;
                if ((long)row >= mend) continue;
                #pragma unroll
                for (int cf=0;cf<8;cf++) {
                    float v = acc[rt][cf][e] + bv[cf];
                    if (RELU) v = fmaxf(v, 0.f);
                    ((__bf16*)out)[row*ldc + col0 + cf*16 + llo] = f2b(v);
                }
            }
        }
    } else {
        float g8[8], b8[8];
        #pragma unroll
        for (int cf=0;cf<8;cf++){ int c = cf*16 + llo; g8[cf] = lng[c]; b8[cf] = lnb[c]; }
        #pragma unroll
        for (int rt=0;rt<2;rt++) {
            #pragma unroll
            for (int e=0;e<4;e++) {
                size_t row = row0 + (size_t)w*32 + rt*16 + lhi*4 + e;
                if ((long)row >= mend) continue;
                float vals[8], s = 0.f, ss = 0.f;
                #pragma unroll
                for (int cf=0;cf<8;cf++) {
                    int c = cf*16 + llo;
                    float r = b2f(resid[row*ldr + c]);
                    float v = acc[rt][cf][e] + bv[cf] + r;
                    vals[cf] = v; s += v; ss += v*v;
                }
                #pragma unroll
                for (int o=1;o<16;o<<=1){ s += __shfl_xor(s,o,64); ss += __shfl_xor(ss,o,64); }
                float mean = s * (1.f/DD);
                float var  = ss * (1.f/DD) - mean*mean;
                float rs   = rsqrtf(var + 1e-5f);
                #pragma unroll
                for (int cf=0;cf<8;cf++) {
                    float v = (vals[cf]-mean)*rs*g8[cf] + b8[cf];
                    ((__bf16*)out)[row*ldc + cf*16 + llo] = f2b(v);
                }
            }
        }
    }
}

// ---------------- streaming K=128 GEMM: W in VGPRs, wave-private LDS ring-3, no barriers ----
template<bool RELU>
__global__ __launch_bounds__(256) void sgemm_k128(const __bf16* __restrict__ A, size_t lda,
    const __bf16* __restrict__ W, const float* __restrict__ bias,
    __bf16* __restrict__ out, size_t ldc, int ngroups)
{
    __shared__ __attribute__((aligned(16))) __bf16 lds[12][2048];
    int w = threadIdx.x >> 6, lane = threadIdx.x & 63;
    int lhi = lane >> 4, llo = lane & 15;
    int col0 = blockIdx.y*128;

    bf16x8 wf[4][8];
    #pragma unroll
    for (int ks=0;ks<4;ks++)
        #pragma unroll
        for (int cf=0;cf<8;cf++)
            wf[ks][cf] = ldfrag(W + (size_t)(col0 + cf*16 + llo)*128 + ks*32 + lhi*8);

    f32x4 bvv[8];
    #pragma unroll
    for (int cf=0;cf<8;cf++){
        if (bias) bvv[cf] = *reinterpret_cast<const f32x4*>(bias + col0 + cf*16 + lhi*4);
        else      bvv[cf] = (f32x4){0.f,0.f,0.f,0.f};
    }

    size_t gsrc[4];
    #pragma unroll
    for (int j=0;j<4;j++){
        int r = j*4 + lhi;
        int u = llo ^ r;
        gsrc[j] = (size_t)r*lda + (size_t)u*8;
    }
    int aoff[4];
    #pragma unroll
    for (int ks=0;ks<4;ks++) aoff[ks] = llo*128 + (((ks<<2)|lhi) ^ llo)*8;

    int gw = blockIdx.x*4 + w, stride = gridDim.x*4;
    int n = (gw < ngroups) ? ((ngroups-1-gw)/stride + 1) : 0;
    __bf16* slab0 = &lds[w*3][0];

    #define SSTAGE(i) { size_t rbase = (size_t)(gw + (size_t)(i)*stride)*16*lda;           \
        __bf16* L = slab0 + ((i)%3)*2048;                                                  \
        gload_lds16(A + rbase + gsrc[0], L);                                               \
        gload_lds16(A + rbase + gsrc[1], L + 512);                                         \
        gload_lds16(A + rbase + gsrc[2], L + 1024);                                        \
        gload_lds16(A + rbase + gsrc[3], L + 1536); }

    if (n > 0) SSTAGE(0);
    if (n > 1) SSTAGE(1);

    for (int i = 0; i < n; ++i) {
        int kept = ((i+1 < n) ? 4 : 0) + ((i >= 2) ? 16 : i*8);
        if      (kept >= 20) asm volatile("s_waitcnt vmcnt(20)" ::: "memory");
        else if (kept == 16) asm volatile("s_waitcnt vmcnt(16)" ::: "memory");
        else if (kept == 12) asm volatile("s_waitcnt vmcnt(12)" ::: "memory");
        else if (kept == 8)  asm volatile("s_waitcnt vmcnt(8)"  ::: "memory");
        else if (kept == 4)  asm volatile("s_waitcnt vmcnt(4)"  ::: "memory");
        else                 asm volatile("s_waitcnt vmcnt(0)"  ::: "memory");

        const __bf16* Ls = slab0 + (i%3)*2048;
        bf16x8 a[4];
        #pragma unroll
        for (int ks=0;ks<4;ks++) a[ks] = *reinterpret_cast<const bf16x8*>(&Ls[aoff[ks]]);

        if (i+2 < n) SSTAGE(i+2);

        f32x4 acc[8];
        #pragma unroll
        for (int cf=0;cf<8;cf++) acc[cf] = (f32x4){0.f,0.f,0.f,0.f};
        #pragma unroll
        for (int ks=0;ks<4;ks++)
            #pragma unroll
            for (int cf=0;cf<8;cf++)
                acc[cf] = __builtin_amdgcn_mfma_f32_16x16x32_bf16(wf[ks][cf], a[ks], acc[cf], 0,0,0);

        size_t grow = (size_t)(gw + (size_t)i*stride)*16 + llo;
        #pragma unroll
        for (int cf=0;cf<8;cf++){
            bf16x4 o;
            #pragma unroll
            for (int e=0;e<4;e++){
                float v = acc[cf][e] + bvv[cf][e];
                if (RELU) v = fmaxf(v, 0.f);
                o[e] = f2b(v);
            }
            *reinterpret_cast<bf16x4*>(out + grow*ldc + col0 + cf*16 + lhi*4) = o;
        }
    }
    #undef SSTAGE
}

// ---------------- fused FFN (64-row blocks, ring-2 prologue-staged, batched W loads) -------
__global__ __launch_bounds__(256) void ffn_kernel(const __bf16* __restrict__ h,
    const __bf16* __restrict__ w1, const float* __restrict__ b1,
    const __bf16* __restrict__ w2, const float* __restrict__ b2,
    const float* __restrict__ lng, const float* __restrict__ lnb,
    float* __restrict__ dout)
{
    __shared__ __attribute__((aligned(16))) __bf16 hring[2][4096];
    __shared__ __attribute__((aligned(16))) __bf16 f1b[8192];
    __shared__ float fl2[2][32][4][2];
    int w = threadIdx.x >> 6, lane = threadIdx.x & 63;
    int lhi = lane >> 4, llo = lane & 15;
    size_t row0 = (size_t)blockIdx.x * 64;

    size_t gsrc[2]; int ldst[2];
    #pragma unroll
    for (int j=0;j<2;j++){
        int i = w*64 + lane + 256*j;
        int r = i >> 4, u = i & 15;
        gsrc[j] = (size_t)r*AW + ((u ^ (r & 15)) << 3);
        ldst[j] = (w*64 + 256*j) * 8;
    }
    #define FSTAGE(slot, g) { const __bf16* src = h + (row0 + (size_t)(g)*32)*AW;          \
        gload_lds16(src + gsrc[0], &hring[slot][0] + ldst[0]);                             \
        gload_lds16(src + gsrc[1], &hring[slot][0] + ldst[1]); }

    f32x4 b1v[4], b2v[2], gv[2], bt2[2];
    #pragma unroll
    for (int c4=0;c4<4;c4++) b1v[c4] = *reinterpret_cast<const f32x4*>(b1 + w*64 + c4*16 + lhi*4);
    #pragma unroll
    for (int c2=0;c2<2;c2++){
        b2v[c2] = *reinterpret_cast<const f32x4*>(b2  + w*32 + c2*16 + lhi*4);
        gv[c2]  = *reinterpret_cast<const f32x4*>(lng + w*32 + c2*16 + lhi*4);
        bt2[c2] = *reinterpret_cast<const f32x4*>(lnb + w*32 + c2*16 + lhi*4);
    }

    FSTAGE(0,0); FSTAGE(1,1);

    for (int g = 0; g < 2; ++g) {
        if (g == 0) asm volatile("s_waitcnt vmcnt(2)" ::: "memory");
        else        asm volatile("s_waitcnt vmcnt(0)" ::: "memory");
        __builtin_amdgcn_s_barrier();
        __builtin_amdgcn_sched_barrier(0);
        const __bf16* Hs = &hring[g][0];

        bf16x8 hb[2][4];
        bf16x4 hres[2][2];
        #pragma unroll
        for (int rf=0;rf<2;rf++){
            int r = rf*16 + llo;
            #pragma unroll
            for (int ks=0;ks<4;ks++)
                hb[rf][ks] = *reinterpret_cast<const bf16x8*>(Hs + r*128 + (((ks*4+lhi) ^ llo) << 3));
            #pragma unroll
            for (int cf=0;cf<2;cf++){
                int unit = w*4 + cf*2 + (lhi>>1);
                hres[cf][rf] = *reinterpret_cast<const bf16x4*>(Hs + r*128 + ((unit ^ llo) << 3) + (lhi & 1)*4);
            }
        }
        asm volatile("s_waitcnt lgkmcnt(0)" ::: "memory");
        __builtin_amdgcn_sched_barrier(0);

        // ---- ff1: batched W1 loads (8 in flight) then MFMA bursts ----
        f32x4 acc1[4][2];
        #pragma unroll
        for (int i=0;i<4;i++){ acc1[i][0] = (f32x4){0,0,0,0}; acc1[i][1] = (f32x4){0,0,0,0}; }
        #pragma unroll
        for (int half=0; half<2; ++half){
            bf16x8 w1f[8];
            #pragma unroll
            for (int i=0;i<8;i++){
                int ks = half*2 + (i>>2), cf2 = i&3;
                w1f[i] = ldfrag(w1 + (size_t)(w*64 + cf2*16 + llo)*128 + ks*32 + lhi*8);
            }
            #pragma unroll
            for (int i=0;i<8;i++){
                int ks = half*2 + (i>>2), cf2 = i&3;
                #pragma unroll
                for (int rf=0;rf<2;rf++)
                    acc1[cf2][rf] = __builtin_amdgcn_mfma_f32_16x16x32_bf16(w1f[i], hb[rf][ks], acc1[cf2][rf], 0,0,0);
            }
        }
        #pragma unroll
        for (int rf=0;rf<2;rf++){
            int r = rf*16 + llo;
            #pragma unroll
            for (int cf2=0;cf2<4;cf2++){
                bf16x4 o;
                #pragma unroll
                for (int e=0;e<4;e++) o[e] = f2b(fmaxf(acc1[cf2][rf][e] + b1v[cf2][e], 0.f));
                int unit = w*8 + cf2*2 + (lhi>>1);
                *reinterpret_cast<bf16x4*>(&f1b[r*256 + ((unit ^ r) << 3) + (lhi&1)*4]) = o;
            }
        }
        asm volatile("s_waitcnt lgkmcnt(0)" ::: "memory");
        __builtin_amdgcn_sched_barrier(0);
        __builtin_amdgcn_s_barrier();

        // ---- ff2: batched W2 loads (8 in flight) then MFMA bursts ----
        f32x4 acc2[2][2];
        acc2[0][0]=(f32x4){0,0,0,0}; acc2[0][1]=(f32x4){0,0,0,0};
        acc2[1][0]=(f32x4){0,0,0,0}; acc2[1][1]=(f32x4){0,0,0,0};
        #pragma unroll
        for (int half=0; half<2; ++half){
            bf16x8 w2f[8];
            #pragma unroll
            for (int i=0;i<8;i++){
                int ks2 = half*4 + (i>>1), cf = i&1;
                w2f[i] = ldfrag(w2 + (size_t)(w*32 + cf*16 + llo)*256 + ks2*32 + lhi*8);
            }
            #pragma unroll
            for (int i=0;i<8;i++){
                int ks2 = half*4 + (i>>1), cf = i&1;
                #pragma unroll
                for (int rf=0;rf<2;rf++){
                    int r = rf*16 + llo;
                    bf16x8 fb = *reinterpret_cast<const bf16x8*>(&f1b[r*256 + (((ks2*4+lhi) ^ r) << 3)]);
                    acc2[cf][rf] = __builtin_amdgcn_mfma_f32_16x16x32_bf16(w2f[i], fb, acc2[cf][rf], 0,0,0);
                }
            }
        }

        float vals[2][2][4]; float s[2] = {0.f,0.f}, ss[2] = {0.f,0.f};
        #pragma unroll
        for (int rf=0;rf<2;rf++)
            #pragma unroll
            for (int cf=0;cf<2;cf++)
                #pragma unroll
                for (int e=0;e<4;e++){
                    float v = acc2[cf][rf][e] + b2v[cf][e] + b2f(hres[cf][rf][e]);
                    vals[rf][cf][e] = v; s[rf] += v; ss[rf] += v*v;
                }
        #pragma unroll
        for (int rf=0;rf<2;rf++){
            s[rf]  += __shfl_xor(s[rf],16,64);  s[rf]  += __shfl_xor(s[rf],32,64);
            ss[rf] += __shfl_xor(ss[rf],16,64); ss[rf] += __shfl_xor(ss[rf],32,64);
            if (lhi == 0){ fl2[g][rf*16+llo][w][0] = s[rf]; fl2[g][rf*16+llo][w][1] = ss[rf]; }
        }
        asm volatile("s_waitcnt lgkmcnt(0)" ::: "memory");
        __builtin_amdgcn_s_barrier();
        #pragma unroll
        for (int rf=0;rf<2;rf++){
            int r = rf*16 + llo;
            float S  = fl2[g][r][0][0]+fl2[g][r][1][0]+fl2[g][r][2][0]+fl2[g][r][3][0];
            float SS = fl2[g][r][0][1]+fl2[g][r][1][1]+fl2[g][r][2][1]+fl2[g][r][3][1];
            float mean = S*(1.f/DD), var = SS*(1.f/DD)-mean*mean, rs = rsqrtf(var+1e-5f);
            size_t grow = row0 + (size_t)g*32 + r;
            #pragma unroll
            for (int cf=0;cf<2;cf++){
                f32x4 o;
                #pragma unroll
                for (int e=0;e<4;e++) o[e] = (vals[rf][cf][e]-mean)*rs*gv[cf][e] + bt2[cf][e];
                *reinterpret_cast<f32x4*>(dout + grow*DD + w*32 + cf*16 + lhi*4) = o;
            }
        }
        if (g == 0) __builtin_amdgcn_s_barrier();
    }
    #undef FSTAGE
}

// ---------------- merged spatial+temporal linear attention ----------------
#define ACH 32
#define SBLKS (CHB*TT*4)
__global__ __launch_bounds__(256) void attn_st_kernel(const __bf16* __restrict__ qkv,
    __bf16* __restrict__ outs, __bf16* __restrict__ outt)
{
    __shared__ __attribute__((aligned(16))) char smem[49664];
    int tid = threadIdx.x;
    int bx = blockIdx.x;

    if (bx < SBLKS) {
        int bt = bx >> 2, g = bx & 3;
        const __bf16* base = qkv + (size_t)bt*NN*384 + g*32;
        __bf16 (*qbuf)[40] = (__bf16(*)[40])(smem);                 // 224x40 @0
        __bf16 (*vbuf)[40] = (__bf16(*)[40])(smem + 17920);         // 224x40
        __bf16 (*kbuf)[40] = (__bf16(*)[40])(smem + 35840);         // 32x40
        __bf16 (*khT)[40]  = (__bf16(*)[40])(smem + 38400);         // 32x40  khatT[m][n]
        __bf16 (*vT)[40]   = (__bf16(*)[40])(smem + 40960);         // 32x40  vT[dd][n]
        float  (*iqt)[224] = (float(*)[224])(smem + 43520);         // [2][224] q inv-norms
        float*  kvp        = (float*)(smem + 45312);                // [4][16][16]
        float*  ksp        = (float*)(smem + 49408);                // [4][16]
        int wave = tid >> 6, lane = tid & 63;
        int lhi = lane >> 4, llo = lane & 15;
        int h = wave >> 1;
        int r8 = tid >> 3, i8 = tid & 7;
        int thead = i8 >> 2, tm4 = (i8 & 3) * 4;

        f32x4 kvs = (f32x4){0,0,0,0}, ksm = (f32x4){0,0,0,0};
        bf16x8 ones8;
        #pragma unroll
        for (int j=0;j<8;j++) ones8[j] = f2b(1.0f);

        for (int c = 0; c < 7; ++c) {
            int c0 = c*32;
            __syncthreads();
            for (int i = tid; i < ACH*12; i += 256) {
                int r = i/12, u = i%12, seg = u>>2, uu = u&3;
                int nn = c0 + r;
                bf16x8 v8 = (bf16x8){};
                if (nn < NN) v8 = *reinterpret_cast<const bf16x8*>(base + (size_t)nn*384 + seg*128 + uu*8);
                if      (seg == 0) *reinterpret_cast<bf16x8*>(&qbuf[nn][uu*8]) = v8;
                else if (seg == 1) *reinterpret_cast<bf16x8*>(&kbuf[r][uu*8])  = v8;
                else               *reinterpret_cast<bf16x8*>(&vbuf[nn][uu*8]) = v8;
            }
            __syncthreads();
            {
                int r = r8, nn = c0 + r8;
                float kv[4], vv[4];
                float sk = 0.f, sq = 0.f;
                #pragma unroll
                for (int j=0;j<4;j++){
                    kv[j] = b2f(kbuf[r][thead*16 + tm4 + j]); sk += kv[j]*kv[j];
                    float qv = b2f(qbuf[nn][thead*16 + tm4 + j]); sq += qv*qv;
                    vv[j] = b2f(vbuf[nn][thead*16 + tm4 + j]);
                }
                sk += __shfl_xor(sk,1,64); sk += __shfl_xor(sk,2,64);
                sq += __shfl_xor(sq,1,64); sq += __shfl_xor(sq,2,64);
                float iv = 1.f/fmaxf(sqrtf(sk), 1e-12f);
                #pragma unroll
                for (int j=0;j<4;j++){
                    khT[thead*16 + tm4 + j][r] = f2b(kv[j]*iv);
                    vT [thead*16 + tm4 + j][r] = f2b(vv[j]);
                }
                if ((i8 & 3) == 0) iqt[thead][nn] = 1.f/fmaxf(sqrtf(sq), 1e-12f);
            }
            __syncthreads();
            if ((c & 1) == (wave & 1)) {
                bf16x8 a = *reinterpret_cast<const bf16x8*>(&khT[h*16 + llo][lhi*8]);
                bf16x8 b = *reinterpret_cast<const bf16x8*>(&vT [h*16 + llo][lhi*8]);
                kvs = __builtin_amdgcn_mfma_f32_16x16x32_bf16(a, b, kvs, 0,0,0);
                ksm = __builtin_amdgcn_mfma_f32_16x16x32_bf16(a, ones8, ksm, 0,0,0);
            }
        }
        #pragma unroll
        for (int e=0;e<4;e++) kvp[wave*256 + (lhi*4+e)*16 + llo] = kvs[e];
        if (llo == 0){
            #pragma unroll
            for (int e=0;e<4;e++) ksp[wave*16 + lhi*4 + e] = ksm[e];
        }
        __syncthreads();
        int pw = wave ^ 1;
        #pragma unroll
        for (int e=0;e<4;e++){
            kvs[e] += kvp[pw*256 + (lhi*4+e)*16 + llo];
            ksm[e] += ksp[pw*16 + lhi*4 + e];
        }
        union { bf16x4 b; s16x4 s; } bk, bs;
        #pragma unroll
        for (int e=0;e<4;e++){ bk.b[e] = f2b(kvs[e]); bs.b[e] = f2b(ksm[e]); }
        for (int t = (wave & 1); t < 13; t += 2) {
            int n0 = t*16;
            union { bf16x4 b; s16x4 s; } aq;
            aq.b = *reinterpret_cast<const bf16x4*>(&qbuf[n0 + llo][h*16 + lhi*4]);
            f32x4 num = __builtin_amdgcn_mfma_f32_16x16x16bf16_1k(aq.s, bk.s, (f32x4){0,0,0,0}, 0,0,0);
            f32x4 den = __builtin_amdgcn_mfma_f32_16x16x16bf16_1k(aq.s, bs.s, (f32x4){0,0,0,0}, 0,0,0);
            #pragma unroll
            for (int e=0;e<4;e++){
                int n = n0 + lhi*4 + e;
                if (n >= NN) continue;
                float iq = iqt[h][n];
                float vv = b2f(vbuf[n][h*16 + llo]);
                float o = (num[e]*iq + (float)NN*vv) / fmaxf(den[e]*iq + (float)NN, 1e-5f);
                outs[((size_t)bt*NN + n)*AW + g*32 + h*16 + llo] = f2b(o);
            }
        }
    } else {
        int tix = bx - SBLKS;
        int b = tix / 104;
        int nn0 = (tix % 104) * 2;
        __bf16 (*rows)[2][384] = (__bf16(*)[2][384])(smem);
        float (*invq)[TT][8]  = (float(*)[TT][8])(smem + 18432);
        float (*invk2)[TT][8] = (float(*)[TT][8])(smem + 19200);
        for (int i = tid; i < TT*2*48; i += 256) {
            int t = i / 96, rem = i % 96;
            int nl = rem / 48, g = rem % 48;
            int nn = nn0 + nl;
            bf16x8 v8 = (bf16x8){};
            if (nn < NN) v8 = *reinterpret_cast<const bf16x8*>(qkv + ((size_t)(b*TT+t)*NN + nn)*384 + g*8);
            *reinterpret_cast<bf16x8*>(&rows[t][nl][g*8]) = v8;
        }
        __syncthreads();
        if (tid < 192) {
            int hh = tid & 7, t = (tid >> 3) % TT, nl = tid / 96;
            bf16x8 q0 = *reinterpret_cast<const bf16x8*>(&rows[t][nl][hh*16]);
            bf16x8 q1 = *reinterpret_cast<const bf16x8*>(&rows[t][nl][hh*16+8]);
            bf16x8 k0 = *reinterpret_cast<const bf16x8*>(&rows[t][nl][128+hh*16]);
            bf16x8 k1 = *reinterpret_cast<const bf16x8*>(&rows[t][nl][128+hh*16+8]);
            float sq = 0.f, sk = 0.f;
            #pragma unroll
            for (int m=0;m<8;m++){
                float a0=b2f(q0[m]), a1=b2f(q1[m]); sq += a0*a0 + a1*a1;
                float c0v=b2f(k0[m]), c1=b2f(k1[m]); sk += c0v*c0v + c1*c1;
            }
            invq[nl][t][hh]  = 1.f/fmaxf(sqrtf(sq), 1e-12f);
            invk2[nl][t][hh] = 1.f/fmaxf(sqrtf(sk), 1e-12f);
        }
        __syncthreads();
        int dd = tid & 15, h = (tid >> 4) & 7, nl = tid >> 7;
        int nn = nn0 + nl;
        float kvs_col[16], ksum[16];
        #pragma unroll
        for (int m=0;m<16;m++){ kvs_col[m]=0.f; ksum[m]=0.f; }
        #pragma unroll
        for (int t=0;t<TT;t++){
            float iv = invk2[nl][t][h];
            bf16x8 k0 = *reinterpret_cast<const bf16x8*>(&rows[t][nl][128+h*16]);
            bf16x8 k1 = *reinterpret_cast<const bf16x8*>(&rows[t][nl][128+h*16+8]);
            float vv = b2f(rows[t][nl][256+h*16+dd]);
            float t2 = iv*vv;
            #pragma unroll
            for (int m=0;m<8;m++){
                float km0 = b2f(k0[m]), km1 = b2f(k1[m]);
                kvs_col[m]   += km0*t2;  ksum[m]   += km0*iv;
                kvs_col[m+8] += km1*t2;  ksum[m+8] += km1*iv;
            }
        }
        #pragma unroll
        for (int t=0;t<TT;t++){
            float iq = invq[nl][t][h];
            bf16x8 q0 = *reinterpret_cast<const bf16x8*>(&rows[t][nl][h*16]);
            bf16x8 q1 = *reinterpret_cast<const bf16x8*>(&rows[t][nl][h*16+8]);
            float num = 0.f, den = 0.f;
            #pragma unroll
            for (int m=0;m<8;m++){
                float qm0 = b2f(q0[m]), qm1 = b2f(q1[m]);
                num += qm0*kvs_col[m]  + qm1*kvs_col[m+8];
                den += qm0*ksum[m]     + qm1*ksum[m+8];
            }
            float vv = b2f(rows[t][nl][256+h*16+dd]);
            float o = (num*iq + (float)TT*vv) / fmaxf(den*iq + (float)TT, 1e-5f);
            if (nn < NN)
                outt[((size_t)(b*TT+t)*NN + nn)*AW + h*16 + dd] = f2b(o);
        }
    }
}

extern "C" void kernel_launch(void* const* d_in, const int* in_sizes, int n_in,
                              void* d_out, int out_size, void* d_ws, size_t ws_size,
                              hipStream_t stream)
{
    const float* x     = (const float*)d_in[0];
    const float* graph = (const float*)d_in[1];
    const float* qkv_w = (const float*)d_in[2];
    const float* out_w = (const float*)d_in[3];
    const float* out_b = (const float*)d_in[4];
    const float* pw_w  = (const float*)d_in[5];
    const float* pw_b  = (const float*)d_in[6];
    const float* fc1_w = (const float*)d_in[7];
    const float* fc1_b = (const float*)d_in[8];
    const float* fc2_w = (const float*)d_in[9];
    const float* fc2_b = (const float*)d_in[10];
    const float* ln1g  = (const float*)d_in[11];
    const float* ln1b  = (const float*)d_in[12];
    const float* ln2g  = (const float*)d_in[13];
    const float* ln2b  = (const float*)d_in[14];
    (void)in_sizes; (void)n_in; (void)out_size; (void)ws_size;

    char* ws = (char*)d_ws;
    size_t off = 0;
    __bf16* abuf = (__bf16*)(ws + off); off += (size_t)MROWS*AW*2;
    __bf16* qkvc = (__bf16*)(ws + off); off += (size_t)CROWS*3*DD*2;
    __bf16* gpad = (__bf16*)(ws + off); off += (size_t)TT*NN*KPAD*2;
    __bf16* qkv_wb = (__bf16*)(ws + off); off += (size_t)2*3*DD*DD*2;
    __bf16* wcomb  = (__bf16*)(ws + off); off += (size_t)DD*AW*2;
    __bf16* fc1_wb = (__bf16*)(ws + off); off += (size_t)2*DD*DD*2;
    __bf16* fc2_wb = (__bf16*)(ws + off); off += (size_t)2*DD*DD*2;
    float*  bias_comb = (float*)(ws + off); off += DD*4;

    dim3 blk(256), blk512(512);

    xcopy_kernel<<<dim3(4096), blk, 0, stream>>>(x, abuf);
    prep_misc_kernel<<<dim3(1024), blk, 0, stream>>>(graph, qkv_w, out_w, out_b, pw_w, pw_b,
        fc1_w, fc2_w, gpad, qkv_wb, wcomb, fc1_wb, fc2_wb, bias_comb);
    propagate_kernel<<<dim3(BB*TT, 4), blk, 0, stream>>>(gpad, abuf);

    for (int hop = 0; hop < 2; ++hop) {
        for (int c = 0; c < BB/CHB; ++c) {
            size_t rowoff = (size_t)c*CROWS;
            sgemm_k128<false><<<dim3(170, 3), blk, 0, stream>>>(
                abuf + rowoff*AW + hop*DD, (size_t)AW, qkv_wb + (size_t)hop*3*DD*DD, nullptr,
                qkvc, (size_t)(3*DD), CROWS/16);
            attn_st_kernel<<<dim3(SBLKS + CHB*104), blk, 0, stream>>>(
                qkvc, abuf + rowoff*AW + 256 + hop*256, abuf + rowoff*AW + 384 + hop*256);
        }
    }

    // h = LN1(x + abuf@wcomb^T + bias_comb) -> abuf cols 0:128 (bf16)
    gemm_kernel<3,false><<<dim3(MROWS/256, 1), blk512, 0, stream>>>(
        abuf, (size_t)AW, wcomb, bias_comb, (void*)abuf, (size_t)AW, AW, MROWS,
        abuf, (size_t)AW, ln1g, ln1b);
    // out = LN2(h + relu(h@fc1^T+b1)@fc2^T + b2) -> d_out f32, fused FFN (64-row blocks)
    ffn_kernel<<<dim3(MROWS/64), blk, 0, stream>>>(
        abuf, fc1_wb, fc1_b, fc2_wb, fc2_b, ln2g, ln2b, (float*)d_out);
}

// Round 21
// 713.842 us; speedup vs baseline: 1.1513x; 1.0032x over previous
//
#include <hip/hip_runtime.h>
#include <hip/hip_bf16.h>

#define BB 64
#define TT 12
#define NN 207
#define DD 128
#define HH 8
#define DH 16
#define MROWS (BB*TT*NN)   // 158976 = 621*256 = 2484*64
#define KPAD 224
#define AW 768             // abuf width: [x | xs1 | s0 | t0 | s1 | t1] each 128
#define CHB 32
#define CROWS (CHB*TT*NN)  // 79488 = 4968*16

typedef __bf16 bf16x8 __attribute__((ext_vector_type(8)));
typedef __bf16 bf16x4 __attribute__((ext_vector_type(4)));
typedef float  f32x4  __attribute__((ext_vector_type(4)));
typedef short  s16x4  __attribute__((ext_vector_type(4)));

__device__ inline float  b2f(__bf16 v){ return (float)v; }
__device__ inline __bf16 f2b(float v){ return (__bf16)v; }
__device__ inline bf16x8 ldfrag(const __bf16* p){ return *reinterpret_cast<const bf16x8*>(p); }

__device__ inline void gload_lds16(const __bf16* g, __bf16* l){
    __builtin_amdgcn_global_load_lds(
        (const __attribute__((address_space(1))) void*)(g),
        (__attribute__((address_space(3))) void*)(l), 16, 0, 0);
}
__device__ inline int swz(int r){ return (r ^ (r>>2)) & 3; }
__device__ inline int pkey(int c){ return (c + (c>>2)) & 3; }

// ---------------- x (f32) -> abuf[:,0:128] bf16 ----------------
__global__ __launch_bounds__(256) void xcopy_kernel(const float* __restrict__ x, __bf16* __restrict__ abuf)
{
    int nt = gridDim.x*256;
    for (int gIdx = blockIdx.x*256 + threadIdx.x; gIdx < MROWS*16; gIdx += nt) {
        int row = gIdx >> 4, c8 = (gIdx & 15)*8;
        const float* s = x + (size_t)row*DD + c8;
        f32x4 a = *reinterpret_cast<const f32x4*>(s);
        f32x4 b = *reinterpret_cast<const f32x4*>(s+4);
        bf16x8 r;
        #pragma unroll
        for (int i=0;i<4;i++){ r[i] = f2b(a[i]); r[i+4] = f2b(b[i]); }
        *reinterpret_cast<bf16x8*>(abuf + (size_t)row*AW + c8) = r;
    }
}

// ---------------- misc prep ----------------
__global__ __launch_bounds__(256) void prep_misc_kernel(
    const float* __restrict__ graph, const float* __restrict__ qkv_w,
    const float* __restrict__ out_w, const float* __restrict__ out_b,
    const float* __restrict__ pw_w,  const float* __restrict__ pw_b,
    const float* __restrict__ fc1_w, const float* __restrict__ fc2_w,
    __bf16* __restrict__ gpad, __bf16* __restrict__ qkv_wb, __bf16* __restrict__ wcomb,
    __bf16* __restrict__ fc1_wb, __bf16* __restrict__ fc2_wb, float* __restrict__ bias_comb)
{
    int nt = gridDim.x*256;
    int tid = blockIdx.x*256 + threadIdx.x;
    for (int i = tid; i < TT*NN*KPAD; i += nt) {
        int k = i % KPAD, r = i / KPAD;
        gpad[i] = (k < NN) ? f2b(graph[(size_t)r*NN + k]) : f2b(0.f);
    }
    for (int i = tid; i < 2*3*DD*DD; i += nt) qkv_wb[i] = f2b(qkv_w[i]);
    for (int i = tid; i < DD*AW; i += nt) {
        int c = i / AW, j = i % AW;
        float v;
        if      (j < 128) v = pw_w[c*128 + j];
        else if (j < 256) v = pw_w[128*128 + c*128 + (j-128)];
        else if (j < 512) v = out_w[c*256 + (j-256)];
        else              v = out_w[128*256 + c*256 + (j-512)];
        wcomb[i] = f2b(v);
    }
    for (int i = tid; i < 2*DD*DD; i += nt) fc1_wb[i] = f2b(fc1_w[i]);
    for (int i = tid; i < 2*DD*DD; i += nt) fc2_wb[i] = f2b(fc2_w[i]);
    for (int i = tid; i < DD; i += nt)
        bias_comb[i] = pw_b[i] + pw_b[128+i] + out_b[i] + out_b[128+i];
}

// ---------------- propagate: abuf[:,128:256] = graph[t] @ abuf[:,0:128]  per (b,t) ----------------
__global__ __launch_bounds__(256) void propagate_kernel(const __bf16* __restrict__ gp,
    __bf16* __restrict__ abuf)
{
    int bt   = blockIdx.x;
    int t    = bt % TT;
    int tile = blockIdx.y;
    int lane = threadIdx.x & 63, w = threadIdx.x >> 6;
    int lhi = lane >> 4, llo = lane & 15;
    __shared__ __attribute__((aligned(16))) __bf16 XT[DD][40];
    const __bf16* xbt  = abuf + (size_t)bt*NN*AW;
    const __bf16* grow = gp + (size_t)t*NN*KPAD;
    int rowbase = tile*64 + w*16;
    f32x4 acc[8];
    #pragma unroll
    for (int i=0;i<8;i++) acc[i] = (f32x4){0.f,0.f,0.f,0.f};
    int arow = rowbase + llo; if (arow > NN-1) arow = NN-1;
    for (int k0=0; k0<KPAD; k0+=32) {
        __syncthreads();
        for (int kl = (threadIdx.x>>7); kl < 32; kl += 2) {
            int kk = k0 + kl, c = threadIdx.x & 127;
            __bf16 xb = (kk < NN) ? xbt[(size_t)kk*AW + c] : f2b(0.f);
            XT[c][(((kl>>3) ^ pkey(c))<<3) | (kl&7)] = xb;
        }
        __syncthreads();
        bf16x8 a = ldfrag(grow + (size_t)arow*KPAD + k0 + lhi*8);
        #pragma unroll
        for (int cf=0;cf<8;cf++){
            int row = cf*16+llo;
            bf16x8 b = *reinterpret_cast<const bf16x8*>(&XT[row][(lhi ^ pkey(row))<<3]);
            acc[cf] = __builtin_amdgcn_mfma_f32_16x16x32_bf16(a, b, acc[cf], 0,0,0);
        }
    }
    #pragma unroll
    for (int e=0;e<4;e++){
        int row = rowbase + lhi*4 + e;
        if (row < NN) {
            #pragma unroll
            for (int cf=0;cf<8;cf++)
                abuf[((size_t)bt*NN + row)*AW + DD + cf*16 + llo] = f2b(acc[cf][e]);
        }
    }
}

// ---------------- R7 LDS-staged GEMM (512 thr, 256x128, ring-3, counted vmcnt) ----------------
// MODE 3: out_bf16 = LN(resid + acc + bias)
template<int MODE, bool RELU>
__global__ __launch_bounds__(512) void gemm_kernel(const __bf16* __restrict__ A, size_t lda,
    const __bf16* __restrict__ W, const float* __restrict__ bias,
    void* out, size_t ldc, int K, int mend,
    const __bf16* __restrict__ resid, size_t ldr,
    const float* __restrict__ lng, const float* __restrict__ lnb)
{
    __shared__ __attribute__((aligned(16))) __bf16 lds[3][12288];
    int w = threadIdx.x >> 6, lane = threadIdx.x & 63;
    int lhi = lane >> 4, llo = lane & 15;
    size_t row0 = (size_t)blockIdx.x*256;
    int col0 = blockIdx.y*128;
    int nt = K >> 5;

    int sA0 = (w*2+0)*64 + lane, sA1 = (w*2+1)*64 + lane, sW = w*64 + lane;
    int rA0 = sA0>>2, uA0 = sA0&3, rA1 = sA1>>2, uA1 = sA1&3, rW = sW>>2, uW = sW&3;
    long gr0 = (long)row0 + rA0; if (gr0 >= mend) gr0 = mend-1;
    long gr1 = (long)row0 + rA1; if (gr1 >= mend) gr1 = mend-1;
    const __bf16* gA0 = A + (size_t)gr0*lda + ((uA0 ^ swz(rA0))<<3);
    const __bf16* gA1 = A + (size_t)gr1*lda + ((uA1 ^ swz(rA1))<<3);
    const __bf16* gW  = W + (size_t)(col0 + rW)*K + ((uW ^ swz(rW))<<3);
    __bf16* base0 = &lds[0][0];

    int aoff[2], woff[8];
    #pragma unroll
    for (int rt=0;rt<2;rt++){
        int rl = w*32 + rt*16 + llo;
        aoff[rt] = rl*32 + ((lhi ^ swz(rl))<<3);
    }
    #pragma unroll
    for (int cf=0;cf<8;cf++){
        int wr = cf*16 + llo;
        woff[cf] = 8192 + wr*32 + ((lhi ^ swz(wr))<<3);
    }

    f32x4 acc[2][8];
    #pragma unroll
    for (int i=0;i<2;i++)
        #pragma unroll
        for (int j=0;j<8;j++) acc[i][j] = (f32x4){0.f,0.f,0.f,0.f};

    #define STAGE(buf, tt) { int k0 = (tt)<<5; __bf16* Lw = base0 + (buf)*12288;           \
        gload_lds16(gA0 + k0, Lw + (w*2+0)*512);                                           \
        gload_lds16(gA1 + k0, Lw + (w*2+1)*512);                                           \
        gload_lds16(gW  + k0, Lw + 8192 + w*512); }

    STAGE(0,0); STAGE(1,1); STAGE(2,2);

    int cur = 0;
    for (int t = 0; t < nt; ++t) {
        if (t <= nt-3)      asm volatile("s_waitcnt vmcnt(6)" ::: "memory");
        else if (t == nt-2) asm volatile("s_waitcnt vmcnt(3)" ::: "memory");
        else                asm volatile("s_waitcnt vmcnt(0)" ::: "memory");
        __builtin_amdgcn_s_barrier();
        __builtin_amdgcn_sched_barrier(0);
        const __bf16* Lb = base0 + cur*12288;
        bf16x8 a[2], b[8];
        #pragma unroll
        for (int rt=0;rt<2;rt++) a[rt] = *reinterpret_cast<const bf16x8*>(&Lb[aoff[rt]]);
        #pragma unroll
        for (int cf=0;cf<8;cf++)  b[cf] = *reinterpret_cast<const bf16x8*>(&Lb[woff[cf]]);
        asm volatile("s_waitcnt lgkmcnt(0)" ::: "memory");
        __builtin_amdgcn_sched_barrier(0);
        __builtin_amdgcn_s_barrier();
        if (t+3 < nt) STAGE(cur, t+3);
        #pragma unroll
        for (int rt=0;rt<2;rt++)
            #pragma unroll
            for (int cf=0;cf<8;cf++)
                acc[rt][cf] = __builtin_amdgcn_mfma_f32_16x16x32_bf16(a[rt], b[cf], acc[rt][cf], 0,0,0);
        cur = (cur == 2) ? 0 : cur + 1;
    }
    #undef STAGE

    float bv[8];
    #pragma unroll
    for (int cf=0;cf<8;cf++) bv[cf] = bias ? bias[col0 + cf*16 + llo] : 0.f;

    if (MODE == 0) {
        #pragma unroll
        for (int rt=0;rt<2;rt++) {
            #pragma unroll
            for (int e=0;e<4;e++) {
                size_t row = row0 + (size_t)w*32 + rt*16 + lhi*4 + e;
                if ((long)row >= mend) continue;
                #pragma unroll
                for (int cf=0;cf<8;cf++) {
                    float v = acc[rt][cf][e] + bv[cf];
                    if (RELU) v = fmaxf(v, 0.f);
                    ((__bf16*)out)[row*ldc + col0 + cf*16 + llo] = f2b(v);
                }
            }
        }
    } else {
        float g8[8], b8[8];
        #pragma unroll
        for (int cf=0;cf<8;cf++){ int c = cf*16 + llo; g8[cf] = lng[c]; b8[cf] = lnb[c]; }
        #pragma unroll
        for (int rt=0;rt<2;rt++) {
            #pragma unroll
            for (int e=0;e<4;e++) {
                size_t row = row0 + (size_t)w*32 + rt*16 + lhi*4 + e;
                if ((long)row >= mend) continue;
                float vals[8], s = 0.f, ss = 0.f;
                #pragma unroll
                for (int cf=0;cf<8;cf++) {
                    int c = cf*16 + llo;
                    float r = b2f(resid[row*ldr + c]);
                    float v = acc[rt][cf][e] + bv[cf] + r;
                    vals[cf] = v; s += v; ss += v*v;
                }
                #pragma unroll
                for (int o=1;o<16;o<<=1){ s += __shfl_xor(s,o,64); ss += __shfl_xor(ss,o,64); }
                float mean = s * (1.f/DD);
                float var  = ss * (1.f/DD) - mean*mean;
                float rs   = rsqrtf(var + 1e-5f);
                #pragma unroll
                for (int cf=0;cf<8;cf++) {
                    float v = (vals[cf]-mean)*rs*g8[cf] + b8[cf];
                    ((__bf16*)out)[row*ldc + cf*16 + llo] = f2b(v);
                }
            }
        }
    }
}

// ---------------- streaming K=128 GEMM: W in VGPRs, wave-private LDS ring-3, no barriers ----
template<bool RELU>
__global__ __launch_bounds__(256) void sgemm_k128(const __bf16* __restrict__ A, size_t lda,
    const __bf16* __restrict__ W, const float* __restrict__ bias,
    __bf16* __restrict__ out, size_t ldc, int ngroups)
{
    __shared__ __attribute__((aligned(16))) __bf16 lds[12][2048];
    int w = threadIdx.x >> 6, lane = threadIdx.x & 63;
    int lhi = lane >> 4, llo = lane & 15;
    int col0 = blockIdx.y*128;

    bf16x8 wf[4][8];
    #pragma unroll
    for (int ks=0;ks<4;ks++)
        #pragma unroll
        for (int cf=0;cf<8;cf++)
            wf[ks][cf] = ldfrag(W + (size_t)(col0 + cf*16 + llo)*128 + ks*32 + lhi*8);

    f32x4 bvv[8];
    #pragma unroll
    for (int cf=0;cf<8;cf++){
        if (bias) bvv[cf] = *reinterpret_cast<const f32x4*>(bias + col0 + cf*16 + lhi*4);
        else      bvv[cf] = (f32x4){0.f,0.f,0.f,0.f};
    }

    size_t gsrc[4];
    #pragma unroll
    for (int j=0;j<4;j++){
        int r = j*4 + lhi;
        int u = llo ^ r;
        gsrc[j] = (size_t)r*lda + (size_t)u*8;
    }
    int aoff[4];
    #pragma unroll
    for (int ks=0;ks<4;ks++) aoff[ks] = llo*128 + (((ks<<2)|lhi) ^ llo)*8;

    int gw = blockIdx.x*4 + w, stride = gridDim.x*4;
    int n = (gw < ngroups) ? ((ngroups-1-gw)/stride + 1) : 0;
    __bf16* slab0 = &lds[w*3][0];

    #define SSTAGE(i) { size_t rbase = (size_t)(gw + (size_t)(i)*stride)*16*lda;           \
        __bf16* L = slab0 + ((i)%3)*2048;                                                  \
        gload_lds16(A + rbase + gsrc[0], L);                                               \
        gload_lds16(A + rbase + gsrc[1], L + 512);                                         \
        gload_lds16(A + rbase + gsrc[2], L + 1024);                                        \
        gload_lds16(A + rbase + gsrc[3], L + 1536); }

    if (n > 0) SSTAGE(0);
    if (n > 1) SSTAGE(1);

    for (int i = 0; i < n; ++i) {
        int kept = ((i+1 < n) ? 4 : 0) + ((i >= 2) ? 16 : i*8);
        if      (kept >= 20) asm volatile("s_waitcnt vmcnt(20)" ::: "memory");
        else if (kept == 16) asm volatile("s_waitcnt vmcnt(16)" ::: "memory");
        else if (kept == 12) asm volatile("s_waitcnt vmcnt(12)" ::: "memory");
        else if (kept == 8)  asm volatile("s_waitcnt vmcnt(8)"  ::: "memory");
        else if (kept == 4)  asm volatile("s_waitcnt vmcnt(4)"  ::: "memory");
        else                 asm volatile("s_waitcnt vmcnt(0)"  ::: "memory");

        const __bf16* Ls = slab0 + (i%3)*2048;
        bf16x8 a[4];
        #pragma unroll
        for (int ks=0;ks<4;ks++) a[ks] = *reinterpret_cast<const bf16x8*>(&Ls[aoff[ks]]);

        if (i+2 < n) SSTAGE(i+2);

        f32x4 acc[8];
        #pragma unroll
        for (int cf=0;cf<8;cf++) acc[cf] = (f32x4){0.f,0.f,0.f,0.f};
        #pragma unroll
        for (int ks=0;ks<4;ks++)
            #pragma unroll
            for (int cf=0;cf<8;cf++)
                acc[cf] = __builtin_amdgcn_mfma_f32_16x16x32_bf16(wf[ks][cf], a[ks], acc[cf], 0,0,0);

        size_t grow = (size_t)(gw + (size_t)i*stride)*16 + llo;
        #pragma unroll
        for (int cf=0;cf<8;cf++){
            bf16x4 o;
            #pragma unroll
            for (int e=0;e<4;e++){
                float v = acc[cf][e] + bvv[cf][e];
                if (RELU) v = fmaxf(v, 0.f);
                o[e] = f2b(v);
            }
            *reinterpret_cast<bf16x4*>(out + grow*ldc + col0 + cf*16 + lhi*4) = o;
        }
    }
    #undef SSTAGE
}

// ---------------- fused FFN (64-row blocks, ring-2 prologue-staged, hoisted W batches) ----
__global__ __launch_bounds__(256) void ffn_kernel(const __bf16* __restrict__ h,
    const __bf16* __restrict__ w1, const float* __restrict__ b1,
    const __bf16* __restrict__ w2, const float* __restrict__ b2,
    const float* __restrict__ lng, const float* __restrict__ lnb,
    float* __restrict__ dout)
{
    __shared__ __attribute__((aligned(16))) __bf16 hring[2][4096];
    __shared__ __attribute__((aligned(16))) __bf16 f1b[8192];
    __shared__ float fl2[2][32][4][2];
    int w = threadIdx.x >> 6, lane = threadIdx.x & 63;
    int lhi = lane >> 4, llo = lane & 15;
    size_t row0 = (size_t)blockIdx.x * 64;

    size_t gsrc[2]; int ldst[2];
    #pragma unroll
    for (int j=0;j<2;j++){
        int i = w*64 + lane + 256*j;
        int r = i >> 4, u = i & 15;
        gsrc[j] = (size_t)r*AW + ((u ^ (r & 15)) << 3);
        ldst[j] = (w*64 + 256*j) * 8;
    }
    #define FSTAGE(slot, g) { const __bf16* src = h + (row0 + (size_t)(g)*32)*AW;          \
        gload_lds16(src + gsrc[0], &hring[slot][0] + ldst[0]);                             \
        gload_lds16(src + gsrc[1], &hring[slot][0] + ldst[1]); }

    f32x4 b1v[4], b2v[2], gv[2], bt2[2];
    #pragma unroll
    for (int c4=0;c4<4;c4++) b1v[c4] = *reinterpret_cast<const f32x4*>(b1 + w*64 + c4*16 + lhi*4);
    #pragma unroll
    for (int c2=0;c2<2;c2++){
        b2v[c2] = *reinterpret_cast<const f32x4*>(b2  + w*32 + c2*16 + lhi*4);
        gv[c2]  = *reinterpret_cast<const f32x4*>(lng + w*32 + c2*16 + lhi*4);
        bt2[c2] = *reinterpret_cast<const f32x4*>(lnb + w*32 + c2*16 + lhi*4);
    }

    FSTAGE(0,0); FSTAGE(1,1);

    for (int g = 0; g < 2; ++g) {
        if (g == 0) asm volatile("s_waitcnt vmcnt(2)" ::: "memory");
        else        asm volatile("s_waitcnt vmcnt(0)" ::: "memory");
        __builtin_amdgcn_s_barrier();
        __builtin_amdgcn_sched_barrier(0);
        const __bf16* Hs = &hring[g][0];

        // hoist: W1 half-0 loads issued BEFORE the LDS reads (latency hides under ds phase)
        bf16x8 w1f[8];
        #pragma unroll
        for (int i=0;i<8;i++){
            int ks = (i>>2), cf2 = i&3;
            w1f[i] = ldfrag(w1 + (size_t)(w*64 + cf2*16 + llo)*128 + ks*32 + lhi*8);
        }

        bf16x8 hb[2][4];
        bf16x4 hres[2][2];
        #pragma unroll
        for (int rf=0;rf<2;rf++){
            int r = rf*16 + llo;
            #pragma unroll
            for (int ks=0;ks<4;ks++)
                hb[rf][ks] = *reinterpret_cast<const bf16x8*>(Hs + r*128 + (((ks*4+lhi) ^ llo) << 3));
            #pragma unroll
            for (int cf=0;cf<2;cf++){
                int unit = w*4 + cf*2 + (lhi>>1);
                hres[cf][rf] = *reinterpret_cast<const bf16x4*>(Hs + r*128 + ((unit ^ llo) << 3) + (lhi & 1)*4);
            }
        }
        asm volatile("s_waitcnt lgkmcnt(0)" ::: "memory");
        __builtin_amdgcn_sched_barrier(0);

        // ---- ff1: half-0 MFMAs, then half-1 loads + MFMAs ----
        f32x4 acc1[4][2];
        #pragma unroll
        for (int i=0;i<4;i++){ acc1[i][0] = (f32x4){0,0,0,0}; acc1[i][1] = (f32x4){0,0,0,0}; }
        #pragma unroll
        for (int i=0;i<8;i++){
            int ks = (i>>2), cf2 = i&3;
            #pragma unroll
            for (int rf=0;rf<2;rf++)
                acc1[cf2][rf] = __builtin_amdgcn_mfma_f32_16x16x32_bf16(w1f[i], hb[rf][ks], acc1[cf2][rf], 0,0,0);
        }
        #pragma unroll
        for (int i=0;i<8;i++){
            int ks = 2 + (i>>2), cf2 = i&3;
            w1f[i] = ldfrag(w1 + (size_t)(w*64 + cf2*16 + llo)*128 + ks*32 + lhi*8);
        }
        #pragma unroll
        for (int i=0;i<8;i++){
            int ks = 2 + (i>>2), cf2 = i&3;
            #pragma unroll
            for (int rf=0;rf<2;rf++)
                acc1[cf2][rf] = __builtin_amdgcn_mfma_f32_16x16x32_bf16(w1f[i], hb[rf][ks], acc1[cf2][rf], 0,0,0);
        }
        #pragma unroll
        for (int rf=0;rf<2;rf++){
            int r = rf*16 + llo;
            #pragma unroll
            for (int cf2=0;cf2<4;cf2++){
                bf16x4 o;
                #pragma unroll
                for (int e=0;e<4;e++) o[e] = f2b(fmaxf(acc1[cf2][rf][e] + b1v[cf2][e], 0.f));
                int unit = w*8 + cf2*2 + (lhi>>1);
                *reinterpret_cast<bf16x4*>(&f1b[r*256 + ((unit ^ r) << 3) + (lhi&1)*4]) = o;
            }
        }
        // hoist: W2 half-0 loads issued BEFORE the f1b lgkm wait + barrier
        bf16x8 w2f[8];
        #pragma unroll
        for (int i=0;i<8;i++){
            int ks2 = (i>>1), cf = i&1;
            w2f[i] = ldfrag(w2 + (size_t)(w*32 + cf*16 + llo)*256 + ks2*32 + lhi*8);
        }
        asm volatile("s_waitcnt lgkmcnt(0)" ::: "memory");
        __builtin_amdgcn_sched_barrier(0);
        __builtin_amdgcn_s_barrier();

        // ---- ff2: half-0 MFMAs, then half-1 loads + MFMAs ----
        f32x4 acc2[2][2];
        acc2[0][0]=(f32x4){0,0,0,0}; acc2[0][1]=(f32x4){0,0,0,0};
        acc2[1][0]=(f32x4){0,0,0,0}; acc2[1][1]=(f32x4){0,0,0,0};
        #pragma unroll
        for (int i=0;i<8;i++){
            int ks2 = (i>>1), cf = i&1;
            #pragma unroll
            for (int rf=0;rf<2;rf++){
                int r = rf*16 + llo;
                bf16x8 fb = *reinterpret_cast<const bf16x8*>(&f1b[r*256 + (((ks2*4+lhi) ^ r) << 3)]);
                acc2[cf][rf] = __builtin_amdgcn_mfma_f32_16x16x32_bf16(w2f[i], fb, acc2[cf][rf], 0,0,0);
            }
        }
        #pragma unroll
        for (int i=0;i<8;i++){
            int ks2 = 4 + (i>>1), cf = i&1;
            w2f[i] = ldfrag(w2 + (size_t)(w*32 + cf*16 + llo)*256 + ks2*32 + lhi*8);
        }
        #pragma unroll
        for (int i=0;i<8;i++){
            int ks2 = 4 + (i>>1), cf = i&1;
            #pragma unroll
            for (int rf=0;rf<2;rf++){
                int r = rf*16 + llo;
                bf16x8 fb = *reinterpret_cast<const bf16x8*>(&f1b[r*256 + (((ks2*4+lhi) ^ r) << 3)]);
                acc2[cf][rf] = __builtin_amdgcn_mfma_f32_16x16x32_bf16(w2f[i], fb, acc2[cf][rf], 0,0,0);
            }
        }

        float vals[2][2][4]; float s[2] = {0.f,0.f}, ss[2] = {0.f,0.f};
        #pragma unroll
        for (int rf=0;rf<2;rf++)
            #pragma unroll
            for (int cf=0;cf<2;cf++)
                #pragma unroll
                for (int e=0;e<4;e++){
                    float v = acc2[cf][rf][e] + b2v[cf][e] + b2f(hres[cf][rf][e]);
                    vals[rf][cf][e] = v; s[rf] += v; ss[rf] += v*v;
                }
        #pragma unroll
        for (int rf=0;rf<2;rf++){
            s[rf]  += __shfl_xor(s[rf],16,64);  s[rf]  += __shfl_xor(s[rf],32,64);
            ss[rf] += __shfl_xor(ss[rf],16,64); ss[rf] += __shfl_xor(ss[rf],32,64);
            if (lhi == 0){ fl2[g][rf*16+llo][w][0] = s[rf]; fl2[g][rf*16+llo][w][1] = ss[rf]; }
        }
        asm volatile("s_waitcnt lgkmcnt(0)" ::: "memory");
        __builtin_amdgcn_s_barrier();
        #pragma unroll
        for (int rf=0;rf<2;rf++){
            int r = rf*16 + llo;
            float S  = fl2[g][r][0][0]+fl2[g][r][1][0]+fl2[g][r][2][0]+fl2[g][r][3][0];
            float SS = fl2[g][r][0][1]+fl2[g][r][1][1]+fl2[g][r][2][1]+fl2[g][r][3][1];
            float mean = S*(1.f/DD), var = SS*(1.f/DD)-mean*mean, rs = rsqrtf(var+1e-5f);
            size_t grow = row0 + (size_t)g*32 + r;
            #pragma unroll
            for (int cf=0;cf<2;cf++){
                f32x4 o;
                #pragma unroll
                for (int e=0;e<4;e++) o[e] = (vals[rf][cf][e]-mean)*rs*gv[cf][e] + bt2[cf][e];
                *reinterpret_cast<f32x4*>(dout + grow*DD + w*32 + cf*16 + lhi*4) = o;
            }
        }
        if (g == 0) __builtin_amdgcn_s_barrier();
    }
    #undef FSTAGE
}

// ---------------- merged spatial+temporal linear attention ----------------
#define ACH 32
#define SBLKS (CHB*TT*4)
__global__ __launch_bounds__(256) void attn_st_kernel(const __bf16* __restrict__ qkv,
    __bf16* __restrict__ outs, __bf16* __restrict__ outt)
{
    __shared__ __attribute__((aligned(16))) char smem[49664];
    int tid = threadIdx.x;
    int bx = blockIdx.x;

    if (bx < SBLKS) {
        int bt = bx >> 2, g = bx & 3;
        const __bf16* base = qkv + (size_t)bt*NN*384 + g*32;
        __bf16 (*qbuf)[40] = (__bf16(*)[40])(smem);                 // 224x40 @0
        __bf16 (*vbuf)[40] = (__bf16(*)[40])(smem + 17920);         // 224x40
        __bf16 (*kbuf)[40] = (__bf16(*)[40])(smem + 35840);         // 32x40
        __bf16 (*khT)[40]  = (__bf16(*)[40])(smem + 38400);         // 32x40  khatT[m][n]
        __bf16 (*vT)[40]   = (__bf16(*)[40])(smem + 40960);         // 32x40  vT[dd][n]
        float  (*iqt)[224] = (float(*)[224])(smem + 43520);         // [2][224] q inv-norms
        float*  kvp        = (float*)(smem + 45312);                // [4][16][16]
        float*  ksp        = (float*)(smem + 49408);                // [4][16]
        int wave = tid >> 6, lane = tid & 63;
        int lhi = lane >> 4, llo = lane & 15;
        int h = wave >> 1;
        int r8 = tid >> 3, i8 = tid & 7;
        int thead = i8 >> 2, tm4 = (i8 & 3) * 4;

        f32x4 kvs = (f32x4){0,0,0,0}, ksm = (f32x4){0,0,0,0};
        bf16x8 ones8;
        #pragma unroll
        for (int j=0;j<8;j++) ones8[j] = f2b(1.0f);

        for (int c = 0; c < 7; ++c) {
            int c0 = c*32;
            __syncthreads();
            for (int i = tid; i < ACH*12; i += 256) {
                int r = i/12, u = i%12, seg = u>>2, uu = u&3;
                int nn = c0 + r;
                bf16x8 v8 = (bf16x8){};
                if (nn < NN) v8 = *reinterpret_cast<const bf16x8*>(base + (size_t)nn*384 + seg*128 + uu*8);
                if      (seg == 0) *reinterpret_cast<bf16x8*>(&qbuf[nn][uu*8]) = v8;
                else if (seg == 1) *reinterpret_cast<bf16x8*>(&kbuf[r][uu*8])  = v8;
                else               *reinterpret_cast<bf16x8*>(&vbuf[nn][uu*8]) = v8;
            }
            __syncthreads();
            {
                int r = r8, nn = c0 + r8;
                float kv[4], vv[4];
                float sk = 0.f, sq = 0.f;
                #pragma unroll
                for (int j=0;j<4;j++){
                    kv[j] = b2f(kbuf[r][thead*16 + tm4 + j]); sk += kv[j]*kv[j];
                    float qv = b2f(qbuf[nn][thead*16 + tm4 + j]); sq += qv*qv;
                    vv[j] = b2f(vbuf[nn][thead*16 + tm4 + j]);
                }
                sk += __shfl_xor(sk,1,64); sk += __shfl_xor(sk,2,64);
                sq += __shfl_xor(sq,1,64); sq += __shfl_xor(sq,2,64);
                float iv = 1.f/fmaxf(sqrtf(sk), 1e-12f);
                #pragma unroll
                for (int j=0;j<4;j++){
                    khT[thead*16 + tm4 + j][r] = f2b(kv[j]*iv);
                    vT [thead*16 + tm4 + j][r] = f2b(vv[j]);
                }
                if ((i8 & 3) == 0) iqt[thead][nn] = 1.f/fmaxf(sqrtf(sq), 1e-12f);
            }
            __syncthreads();
            if ((c & 1) == (wave & 1)) {
                bf16x8 a = *reinterpret_cast<const bf16x8*>(&khT[h*16 + llo][lhi*8]);
                bf16x8 b = *reinterpret_cast<const bf16x8*>(&vT [h*16 + llo][lhi*8]);
                kvs = __builtin_amdgcn_mfma_f32_16x16x32_bf16(a, b, kvs, 0,0,0);
                ksm = __builtin_amdgcn_mfma_f32_16x16x32_bf16(a, ones8, ksm, 0,0,0);
            }
        }
        #pragma unroll
        for (int e=0;e<4;e++) kvp[wave*256 + (lhi*4+e)*16 + llo] = kvs[e];
        if (llo == 0){
            #pragma unroll
            for (int e=0;e<4;e++) ksp[wave*16 + lhi*4 + e] = ksm[e];
        }
        __syncthreads();
        int pw = wave ^ 1;
        #pragma unroll
        for (int e=0;e<4;e++){
            kvs[e] += kvp[pw*256 + (lhi*4+e)*16 + llo];
            ksm[e] += ksp[pw*16 + lhi*4 + e];
        }
        union { bf16x4 b; s16x4 s; } bk, bs;
        #pragma unroll
        for (int e=0;e<4;e++){ bk.b[e] = f2b(kvs[e]); bs.b[e] = f2b(ksm[e]); }
        for (int t = (wave & 1); t < 13; t += 2) {
            int n0 = t*16;
            union { bf16x4 b; s16x4 s; } aq;
            aq.b = *reinterpret_cast<const bf16x4*>(&qbuf[n0 + llo][h*16 + lhi*4]);
            f32x4 num = __builtin_amdgcn_mfma_f32_16x16x16bf16_1k(aq.s, bk.s, (f32x4){0,0,0,0}, 0,0,0);
            f32x4 den = __builtin_amdgcn_mfma_f32_16x16x16bf16_1k(aq.s, bs.s, (f32x4){0,0,0,0}, 0,0,0);
            #pragma unroll
            for (int e=0;e<4;e++){
                int n = n0 + lhi*4 + e;
                if (n >= NN) continue;
                float iq = iqt[h][n];
                float vv = b2f(vbuf[n][h*16 + llo]);
                float o = (num[e]*iq + (float)NN*vv) / fmaxf(den[e]*iq + (float)NN, 1e-5f);
                outs[((size_t)bt*NN + n)*AW + g*32 + h*16 + llo] = f2b(o);
            }
        }
    } else {
        int tix = bx - SBLKS;
        int b = tix / 104;
        int nn0 = (tix % 104) * 2;
        __bf16 (*rows)[2][384] = (__bf16(*)[2][384])(smem);
        float (*invq)[TT][8]  = (float(*)[TT][8])(smem + 18432);
        float (*invk2)[TT][8] = (float(*)[TT][8])(smem + 19200);
        for (int i = tid; i < TT*2*48; i += 256) {
            int t = i / 96, rem = i % 96;
            int nl = rem / 48, g = rem % 48;
            int nn = nn0 + nl;
            bf16x8 v8 = (bf16x8){};
            if (nn < NN) v8 = *reinterpret_cast<const bf16x8*>(qkv + ((size_t)(b*TT+t)*NN + nn)*384 + g*8);
            *reinterpret_cast<bf16x8*>(&rows[t][nl][g*8]) = v8;
        }
        __syncthreads();
        if (tid < 192) {
            int hh = tid & 7, t = (tid >> 3) % TT, nl = tid / 96;
            bf16x8 q0 = *reinterpret_cast<const bf16x8*>(&rows[t][nl][hh*16]);
            bf16x8 q1 = *reinterpret_cast<const bf16x8*>(&rows[t][nl][hh*16+8]);
            bf16x8 k0 = *reinterpret_cast<const bf16x8*>(&rows[t][nl][128+hh*16]);
            bf16x8 k1 = *reinterpret_cast<const bf16x8*>(&rows[t][nl][128+hh*16+8]);
            float sq = 0.f, sk = 0.f;
            #pragma unroll
            for (int m=0;m<8;m++){
                float a0=b2f(q0[m]), a1=b2f(q1[m]); sq += a0*a0 + a1*a1;
                float c0v=b2f(k0[m]), c1=b2f(k1[m]); sk += c0v*c0v + c1*c1;
            }
            invq[nl][t][hh]  = 1.f/fmaxf(sqrtf(sq), 1e-12f);
            invk2[nl][t][hh] = 1.f/fmaxf(sqrtf(sk), 1e-12f);
        }
        __syncthreads();
        int dd = tid & 15, h = (tid >> 4) & 7, nl = tid >> 7;
        int nn = nn0 + nl;
        float kvs_col[16], ksum[16];
        #pragma unroll
        for (int m=0;m<16;m++){ kvs_col[m]=0.f; ksum[m]=0.f; }
        #pragma unroll
        for (int t=0;t<TT;t++){
            float iv = invk2[nl][t][h];
            bf16x8 k0 = *reinterpret_cast<const bf16x8*>(&rows[t][nl][128+h*16]);
            bf16x8 k1 = *reinterpret_cast<const bf16x8*>(&rows[t][nl][128+h*16+8]);
            float vv = b2f(rows[t][nl][256+h*16+dd]);
            float t2 = iv*vv;
            #pragma unroll
            for (int m=0;m<8;m++){
                float km0 = b2f(k0[m]), km1 = b2f(k1[m]);
                kvs_col[m]   += km0*t2;  ksum[m]   += km0*iv;
                kvs_col[m+8] += km1*t2;  ksum[m+8] += km1*iv;
            }
        }
        #pragma unroll
        for (int t=0;t<TT;t++){
            float iq = invq[nl][t][h];
            bf16x8 q0 = *reinterpret_cast<const bf16x8*>(&rows[t][nl][h*16]);
            bf16x8 q1 = *reinterpret_cast<const bf16x8*>(&rows[t][nl][h*16+8]);
            float num = 0.f, den = 0.f;
            #pragma unroll
            for (int m=0;m<8;m++){
                float qm0 = b2f(q0[m]), qm1 = b2f(q1[m]);
                num += qm0*kvs_col[m]  + qm1*kvs_col[m+8];
                den += qm0*ksum[m]     + qm1*ksum[m+8];
            }
            float vv = b2f(rows[t][nl][256+h*16+dd]);
            float o = (num*iq + (float)TT*vv) / fmaxf(den*iq + (float)TT, 1e-5f);
            if (nn < NN)
                outt[((size_t)(b*TT+t)*NN + nn)*AW + h*16 + dd] = f2b(o);
        }
    }
}

extern "C" void kernel_launch(void* const* d_in, const int* in_sizes, int n_in,
                              void* d_out, int out_size, void* d_ws, size_t ws_size,
                              hipStream_t stream)
{
    const float* x     = (const float*)d_in[0];
    const float* graph = (const float*)d_in[1];
    const float* qkv_w = (const float*)d_in[2];
    const float* out_w = (const float*)d_in[3];
    const float* out_b = (const float*)d_in[4];
    const float* pw_w  = (const float*)d_in[5];
    const float* pw_b  = (const float*)d_in[6];
    const float* fc1_w = (const float*)d_in[7];
    const float* fc1_b = (const float*)d_in[8];
    const float* fc2_w = (const float*)d_in[9];
    const float* fc2_b = (const float*)d_in[10];
    const float* ln1g  = (const float*)d_in[11];
    const float* ln1b  = (const float*)d_in[12];
    const float* ln2g  = (const float*)d_in[13];
    const float* ln2b  = (const float*)d_in[14];
    (void)in_sizes; (void)n_in; (void)out_size; (void)ws_size;

    char* ws = (char*)d_ws;
    size_t off = 0;
    __bf16* abuf = (__bf16*)(ws + off); off += (size_t)MROWS*AW*2;
    __bf16* qkvc = (__bf16*)(ws + off); off += (size_t)CROWS*3*DD*2;
    __bf16* gpad = (__bf16*)(ws + off); off += (size_t)TT*NN*KPAD*2;
    __bf16* qkv_wb = (__bf16*)(ws + off); off += (size_t)2*3*DD*DD*2;
    __bf16* wcomb  = (__bf16*)(ws + off); off += (size_t)DD*AW*2;
    __bf16* fc1_wb = (__bf16*)(ws + off); off += (size_t)2*DD*DD*2;
    __bf16* fc2_wb = (__bf16*)(ws + off); off += (size_t)2*DD*DD*2;
    float*  bias_comb = (float*)(ws + off); off += DD*4;

    dim3 blk(256), blk512(512);

    xcopy_kernel<<<dim3(4096), blk, 0, stream>>>(x, abuf);
    prep_misc_kernel<<<dim3(1024), blk, 0, stream>>>(graph, qkv_w, out_w, out_b, pw_w, pw_b,
        fc1_w, fc2_w, gpad, qkv_wb, wcomb, fc1_wb, fc2_wb, bias_comb);
    propagate_kernel<<<dim3(BB*TT, 4), blk, 0, stream>>>(gpad, abuf);

    for (int hop = 0; hop < 2; ++hop) {
        for (int c = 0; c < BB/CHB; ++c) {
            size_t rowoff = (size_t)c*CROWS;
            sgemm_k128<false><<<dim3(170, 3), blk, 0, stream>>>(
                abuf + rowoff*AW + hop*DD, (size_t)AW, qkv_wb + (size_t)hop*3*DD*DD, nullptr,
                qkvc, (size_t)(3*DD), CROWS/16);
            attn_st_kernel<<<dim3(SBLKS + CHB*104), blk, 0, stream>>>(
                qkvc, abuf + rowoff*AW + 256 + hop*256, abuf + rowoff*AW + 384 + hop*256);
        }
    }

    // h = LN1(x + abuf@wcomb^T + bias_comb) -> abuf cols 0:128 (bf16)
    gemm_kernel<3,false><<<dim3(MROWS/256, 1), blk512, 0, stream>>>(
        abuf, (size_t)AW, wcomb, bias_comb, (void*)abuf, (size_t)AW, AW, MROWS,
        abuf, (size_t)AW, ln1g, ln1b);
    // out = LN2(h + relu(h@fc1^T+b1)@fc2^T + b2) -> d_out f32, fused FFN (64-row blocks)
    ffn_kernel<<<dim3(MROWS/64), blk, 0, stream>>>(
        abuf, fc1_wb, fc1_b, fc2_wb, fc2_b, ln2g, ln2b, (float*)d_out);
}